// Round 2
// baseline (17094.325 us; speedup 1.0000x reference)
//
#include <hip/hip_runtime.h>
#include <math.h>

#define N_NODES 20000
#define N_EDGES 640000
#define HEADS 4
#define DIM 64
#define CH 256        // HEADS*DIM
#define LAYERS 4
#define HID 512
#define G4 2048       // 4*HID
#define EPS 1e-5f
#define SLOPE 0.2f

#define NC ((size_t)N_NODES*CH)               // 5,120,000 floats
#define NHf ((size_t)N_NODES*HID)             // 10,240,000 floats

// ---------------- helpers ----------------
__device__ __forceinline__ float wave_red_sum(float v){
#pragma unroll
  for (int off = 32; off; off >>= 1) v += __shfl_xor(v, off, 64);
  return v;
}

// ---------------- CSR build ----------------
__global__ void k_hist(const int* __restrict__ dst, int* __restrict__ cnt){
  int e = blockIdx.x * 256 + threadIdx.x;
  if (e < N_EDGES) atomicAdd(&cnt[dst[e]], 1);
}

__global__ __launch_bounds__(1024) void k_scan(const int* __restrict__ cnt,
                                               int* __restrict__ indptr,
                                               int* __restrict__ cursor){
  __shared__ int buf[1024];
  __shared__ int carry;
  if (threadIdx.x == 0) carry = 0;
  __syncthreads();
  for (int base = 0; base < N_NODES; base += 1024){
    int i = base + threadIdx.x;
    int v = (i < N_NODES) ? cnt[i] : 0;
    buf[threadIdx.x] = v;
    __syncthreads();
#pragma unroll
    for (int off = 1; off < 1024; off <<= 1){
      int t = (threadIdx.x >= off) ? buf[threadIdx.x - off] : 0;
      __syncthreads();
      buf[threadIdx.x] += t;
      __syncthreads();
    }
    int excl = buf[threadIdx.x] - v;
    if (i < N_NODES){
      indptr[i] = carry + excl;
      cursor[i] = carry + excl;
    }
    __syncthreads();
    if (threadIdx.x == 0) carry += buf[1023];
    __syncthreads();
  }
  if (threadIdx.x == 0) indptr[N_NODES] = carry;   // == E
}

__global__ void k_scatter(const int* __restrict__ dst, int* __restrict__ cursor,
                          int* __restrict__ eid){
  int e = blockIdx.x * 256 + threadIdx.x;
  if (e < N_EDGES){
    int pos = atomicAdd(&cursor[dst[e]], 1);
    eid[pos] = e;
  }
}

// ---------------- layer-0 transform (K=2) ----------------
__global__ void k_xf0(const float* __restrict__ x, const float* __restrict__ Wl,
                      const float* __restrict__ Wr, float* __restrict__ xl,
                      float* __restrict__ xr){
  int idx = blockIdx.x * 256 + threadIdx.x;   // grid sized exactly N*C/256
  int n = idx >> 8, cx = idx & 255;
  float x0 = x[n * 2], x1 = x[n * 2 + 1];
  xl[idx] = fmaf(x0, Wl[cx], x1 * Wl[CH + cx]);
  xr[idx] = fmaf(x0, Wr[cx], x1 * Wr[CH + cx]);
}

// ---------------- generic f32 GEMM: C = A1*B1(+A2*B2) + bias1 + bias2 ----------------
// B layout: bt ? B[j*K + k] (row-major [Nc,K], i.e. W) : B[k*Nc + j] (row-major [K,Nc])
__global__ __launch_bounds__(256) void k_gemm(
    const float* __restrict__ A1, const float* __restrict__ B1, int K1, int bt1,
    const float* __restrict__ A2, const float* __restrict__ B2, int K2, int bt2,
    const float* __restrict__ bias1, const float* __restrict__ bias2,
    float* __restrict__ Cc, int M, int Nc)
{
  __shared__ float As[16][132];
  __shared__ float Bs[16][132];
  const int tid = threadIdx.x;
  const int tx = tid & 15, ty = tid >> 4;
  const int m0 = blockIdx.x * 128, n0 = blockIdx.y * 128;
  float acc[2][2][4][4];
#pragma unroll
  for (int a = 0; a < 2; a++)
#pragma unroll
    for (int b = 0; b < 2; b++)
#pragma unroll
      for (int i = 0; i < 4; i++)
#pragma unroll
        for (int j = 0; j < 4; j++) acc[a][b][i][j] = 0.f;

  for (int ph = 0; ph < 2; ++ph){
    const float* A = ph ? A2 : A1;
    const float* B = ph ? B2 : B1;
    const int K  = ph ? K2 : K1;
    const int bt = ph ? bt2 : bt1;
    if (K == 0 || A == nullptr) continue;
    for (int k0 = 0; k0 < K; k0 += 16){
#pragma unroll
      for (int i = 0; i < 8; i++){
        int id = tid + i * 256;
        int kk = id & 15, r = id >> 4;
        int m = m0 + r;
        As[kk][r] = (m < M) ? A[(size_t)m * K + (k0 + kk)] : 0.f;
      }
      if (bt){
#pragma unroll
        for (int i = 0; i < 8; i++){
          int id = tid + i * 256;
          int kk = id & 15, j = id >> 4;
          Bs[kk][j] = B[(size_t)(n0 + j) * K + (k0 + kk)];
        }
      } else {
#pragma unroll
        for (int i = 0; i < 8; i++){
          int id = tid + i * 256;
          int j = id & 127, kk = id >> 7;
          Bs[kk][j] = B[(size_t)(k0 + kk) * Nc + (n0 + j)];
        }
      }
      __syncthreads();
#pragma unroll
      for (int kk = 0; kk < 16; kk++){
        float4 a0 = *(const float4*)&As[kk][ty * 4];
        float4 a1 = *(const float4*)&As[kk][ty * 4 + 64];
        float4 b0 = *(const float4*)&Bs[kk][tx * 4];
        float4 b1 = *(const float4*)&Bs[kk][tx * 4 + 64];
        float av[2][4] = {{a0.x, a0.y, a0.z, a0.w}, {a1.x, a1.y, a1.z, a1.w}};
        float bv[2][4] = {{b0.x, b0.y, b0.z, b0.w}, {b1.x, b1.y, b1.z, b1.w}};
#pragma unroll
        for (int bi = 0; bi < 2; bi++)
#pragma unroll
          for (int i = 0; i < 4; i++)
#pragma unroll
            for (int bj = 0; bj < 2; bj++)
#pragma unroll
              for (int j = 0; j < 4; j++)
                acc[bi][bj][i][j] = fmaf(av[bi][i], bv[bj][j], acc[bi][bj][i][j]);
      }
      __syncthreads();
    }
  }
  // epilogue
#pragma unroll
  for (int bj = 0; bj < 2; bj++){
    int c0 = n0 + bj * 64 + tx * 4;
    float bb[4] = {0.f, 0.f, 0.f, 0.f};
    if (bias1){
#pragma unroll
      for (int j = 0; j < 4; j++) bb[j] += bias1[c0 + j];
    }
    if (bias2){
#pragma unroll
      for (int j = 0; j < 4; j++) bb[j] += bias2[c0 + j];
    }
#pragma unroll
    for (int bi = 0; bi < 2; bi++)
#pragma unroll
      for (int i = 0; i < 4; i++){
        int m = m0 + bi * 64 + ty * 4 + i;
        if (m < M){
          float4 v = make_float4(acc[bi][bj][i][0] + bb[0], acc[bi][bj][i][1] + bb[1],
                                 acc[bi][bj][i][2] + bb[2], acc[bi][bj][i][3] + bb[3]);
          *(float4*)&Cc[(size_t)m * Nc + c0] = v;
        }
      }
  }
}

// ---------------- edge logits: one wave per edge ----------------
__global__ __launch_bounds__(256) void k_edge(
    const int* __restrict__ src, const int* __restrict__ dst,
    const float* __restrict__ ea, const float* __restrict__ xl,
    const float* __restrict__ xr, const float* __restrict__ We,
    const float* __restrict__ att, float* __restrict__ logits)
{
  int gw = (blockIdx.x * 256 + threadIdx.x) >> 6;
  int lane = threadIdx.x & 63;
  int nw = (gridDim.x * 256) >> 6;
  for (int e = gw; e < N_EDGES; e += nw){
    int s = src[e], d = dst[e];
    float av = ea[e];
    float lg[4];
#pragma unroll
    for (int h = 0; h < 4; h++){
      int cc = h * 64 + lane;
      float v = xl[(size_t)s * CH + cc] + xr[(size_t)d * CH + cc] + av * We[cc];
      v = v > 0.f ? v : SLOPE * v;
      v *= att[cc];
      lg[h] = wave_red_sum(v);
    }
    if (lane == 0)
      *reinterpret_cast<float4*>(logits + (size_t)e * 4) =
          make_float4(lg[0], lg[1], lg[2], lg[3]);
  }
}

// ---------------- per-dst softmax over incoming edges (alpha in place) ----------------
__global__ __launch_bounds__(256) void k_segsm(const int* __restrict__ indptr,
                                               const int* __restrict__ eid,
                                               float* __restrict__ logits)
{
  int gw = (blockIdx.x * 256 + threadIdx.x) >> 6;
  int lane = threadIdx.x & 63;
  int nw = (gridDim.x * 256) >> 6;
  for (int n = gw; n < N_NODES; n += nw){
    int s0 = indptr[n], s1 = indptr[n + 1];
    float4 mx = make_float4(-1e30f, -1e30f, -1e30f, -1e30f);
    for (int i = s0 + lane; i < s1; i += 64){
      const float4 lg = *reinterpret_cast<const float4*>(logits + (size_t)eid[i] * 4);
      mx.x = fmaxf(mx.x, lg.x); mx.y = fmaxf(mx.y, lg.y);
      mx.z = fmaxf(mx.z, lg.z); mx.w = fmaxf(mx.w, lg.w);
    }
#pragma unroll
    for (int off = 32; off; off >>= 1){
      mx.x = fmaxf(mx.x, __shfl_xor(mx.x, off, 64));
      mx.y = fmaxf(mx.y, __shfl_xor(mx.y, off, 64));
      mx.z = fmaxf(mx.z, __shfl_xor(mx.z, off, 64));
      mx.w = fmaxf(mx.w, __shfl_xor(mx.w, off, 64));
    }
    float4 den = make_float4(0.f, 0.f, 0.f, 0.f);
    for (int i = s0 + lane; i < s1; i += 64){
      const float4 lg = *reinterpret_cast<const float4*>(logits + (size_t)eid[i] * 4);
      den.x += expf(lg.x - mx.x); den.y += expf(lg.y - mx.y);
      den.z += expf(lg.z - mx.z); den.w += expf(lg.w - mx.w);
    }
    den.x = wave_red_sum(den.x); den.y = wave_red_sum(den.y);
    den.z = wave_red_sum(den.z); den.w = wave_red_sum(den.w);
    float4 inv;
    inv.x = 1.f / den.x; inv.y = 1.f / den.y; inv.z = 1.f / den.z; inv.w = 1.f / den.w;
    for (int i = s0 + lane; i < s1; i += 64){
      float* p = logits + (size_t)eid[i] * 4;
      const float4 lg = *reinterpret_cast<const float4*>(p);
      *reinterpret_cast<float4*>(p) =
          make_float4(expf(lg.x - mx.x) * inv.x, expf(lg.y - mx.y) * inv.y,
                      expf(lg.z - mx.z) * inv.z, expf(lg.w - mx.w) * inv.w);
    }
  }
}

// ---------------- aggregate: block per dst node, thread = channel ----------------
__global__ __launch_bounds__(256) void k_agg(
    const int* __restrict__ indptr, const int* __restrict__ eid,
    const int* __restrict__ src, const float* __restrict__ alpha,
    const float* __restrict__ xl, const float* __restrict__ bias,
    float* __restrict__ xout)
{
  int n = blockIdx.x;
  int t = threadIdx.x;
  int h = t >> 6;
  int s0 = indptr[n], s1 = indptr[n + 1];
  float acc = 0.f;
  for (int i = s0; i < s1; i++){
    int e = eid[i];
    int s = src[e];
    float a = alpha[(size_t)e * 4 + h];
    acc = fmaf(a, xl[(size_t)s * CH + t], acc);
  }
  float v = acc + bias[t];
  xout[(size_t)n * CH + t] = v > 0.f ? v : 0.f;   // relu
}

// ---------------- LSTM cell + JK score partial ----------------
__global__ __launch_bounds__(512) void k_cell(
    const float* __restrict__ gates, float* __restrict__ h, float* __restrict__ c,
    const float* __restrict__ jkw, float* __restrict__ score, int accum)
{
  int n = blockIdx.x, j = threadIdx.x;
  size_t gb = (size_t)n * G4;
  float gi = gates[gb + j];
  float gf = gates[gb + 512 + j];
  float gg = gates[gb + 1024 + j];
  float go = gates[gb + 1536 + j];
  size_t hb = (size_t)n * HID + j;
  float cv = c[hb];
  float iv = 1.f / (1.f + expf(-gi));
  float fv = 1.f / (1.f + expf(-gf));
  float ov = 1.f / (1.f + expf(-go));
  float cn = fv * cv + iv * tanhf(gg);
  float hn = ov * tanhf(cn);
  c[hb] = cn;
  h[hb] = hn;
  float p = wave_red_sum(hn * jkw[j]);
  __shared__ float red[8];
  int lane = j & 63, w = j >> 6;
  if (lane == 0) red[w] = p;
  __syncthreads();
  if (j == 0){
    float tot = red[0] + red[1] + red[2] + red[3] + red[4] + red[5] + red[6] + red[7];
    if (accum) score[n] += tot; else score[n] = tot;
  }
}

// ---------------- JK softmax combine ----------------
__global__ __launch_bounds__(256) void k_jk(const float* __restrict__ scores,
                                            const float* __restrict__ xs,
                                            float* __restrict__ out)
{
  int n = blockIdx.x, cx = threadIdx.x;
  float s0 = scores[n], s1 = scores[N_NODES + n];
  float s2 = scores[2 * N_NODES + n], s3 = scores[3 * N_NODES + n];
  float mx = fmaxf(fmaxf(s0, s1), fmaxf(s2, s3));
  float e0 = expf(s0 - mx), e1 = expf(s1 - mx), e2 = expf(s2 - mx), e3 = expf(s3 - mx);
  float inv = 1.f / (e0 + e1 + e2 + e3);
  size_t idx = (size_t)n * CH + cx;
  float v = e0 * xs[idx] + e1 * xs[NC + idx] + e2 * xs[2 * NC + idx] +
            e3 * xs[3 * NC + idx];
  out[idx] = v * inv;
}

// ---------------- batch-norm style final ----------------
__global__ __launch_bounds__(256) void k_bnred(const float* __restrict__ out,
                                               float* __restrict__ sums)
{
  int cx = threadIdx.x;
  float s = 0.f, s2 = 0.f;
  for (int n = blockIdx.x; n < N_NODES; n += gridDim.x){
    float v = out[(size_t)n * CH + cx];
    s += v;
    s2 = fmaf(v, v, s2);
  }
  atomicAdd(&sums[cx], s);
  atomicAdd(&sums[CH + cx], s2);
}

__global__ __launch_bounds__(256) void k_bnapply(float* __restrict__ out,
                                                 const float* __restrict__ sums,
                                                 const float* __restrict__ gamma,
                                                 const float* __restrict__ beta)
{
  int idx = blockIdx.x * 256 + threadIdx.x;  // grid sized exactly N*C/256
  int cx = idx & 255;
  const float invN = 1.f / (float)N_NODES;
  float mean = sums[cx] * invN;
  float var = sums[CH + cx] * invN - mean * mean;
  out[idx] = (out[idx] - mean) * rsqrtf(var + EPS) * gamma[cx] + beta[cx];
}

// ---------------- host ----------------
extern "C" void kernel_launch(void* const* d_in, const int* in_sizes, int n_in,
                              void* d_out, int out_size, void* d_ws, size_t ws_size,
                              hipStream_t stream)
{
  const float* x     = (const float*)d_in[0];
  const int*   eidx  = (const int*)d_in[1];
  const int*   srcp  = eidx;
  const int*   dstp  = eidx + N_EDGES;
  const float* ea    = (const float*)d_in[2];
  const float* Wl0   = (const float*)d_in[3];
  const float* Wr0   = (const float*)d_in[4];
  const float* We0   = (const float*)d_in[5];
  const float* att0  = (const float*)d_in[6];
  const float* b0    = (const float*)d_in[7];
  const float* WlR   = (const float*)d_in[8];
  const float* WrR   = (const float*)d_in[9];
  const float* WeR   = (const float*)d_in[10];
  const float* attR  = (const float*)d_in[11];
  const float* bR    = (const float*)d_in[12];
  const float* Wih_f = (const float*)d_in[13];
  const float* Whh_f = (const float*)d_in[14];
  const float* bih_f = (const float*)d_in[15];
  const float* bhh_f = (const float*)d_in[16];
  const float* Wih_b = (const float*)d_in[17];
  const float* Whh_b = (const float*)d_in[18];
  const float* bih_b = (const float*)d_in[19];
  const float* bhh_b = (const float*)d_in[20];
  const float* jkw   = (const float*)d_in[21];
  const float* gamma = (const float*)d_in[23];
  const float* beta  = (const float*)d_in[24];

  // ---------- adaptive workspace layout (float units) ----------
  const size_t ws_f   = ws_size / 4;
  const size_t SHf    = 4 * NC;                 // xs region: 20,480,000
  const size_t smallf = 4 * (size_t)N_NODES + 512;   // scores + sums
  // GAT scratch need: xl + xr + logits + int region (indptr/cursor/eid as ints)
  const size_t gat_need = SHf + 2 * NC + 4 * (size_t)N_EDGES
                        + (2 * (size_t)N_NODES + 1 + (size_t)N_EDGES) + smallf;
  // LSTM fixed: h + c
  const size_t lstm_base = SHf + 2 * NHf;
  long long gc_ll = ((long long)ws_f - (long long)smallf - (long long)lstm_base) / G4;
  if (gc_ll > N_NODES) gc_ll = N_NODES;
  if (gc_ll < 128 || gat_need > ws_f) return;   // ws too small: leave output poisoned
  const int GC = (int)gc_ll;                    // LSTM gate-chunk (nodes)

  float* ws     = (float*)d_ws;
  float* xs     = ws;                           // [4][N][CH]
  // GAT phase (dead before LSTM phase)
  float* xl     = ws + SHf;
  float* xr     = xl + NC;
  float* logit  = xr + NC;                      // [E][4]
  int*   ibase  = (int*)(logit + 4 * (size_t)N_EDGES);
  int*   indptr = ibase;                        // N+1
  int*   cursor = ibase + (N_NODES + 1);        // N
  int*   eid    = cursor + N_NODES;             // E
  // LSTM phase (reuses GAT region)
  float* hbuf   = ws + SHf;                     // [N][HID]
  float* cbuf   = hbuf + NHf;                   // [N][HID]
  float* gates  = cbuf + NHf;                   // [GC][G4]
  // persistent small (at end of ws)
  float* scores = ws + (ws_f - smallf);         // [4][N]
  float* sums   = scores + 4 * (size_t)N_NODES; // [512]

  // ---- CSR by dst ----
  hipMemsetAsync(cursor, 0, N_NODES * sizeof(int), stream);
  k_hist<<<(N_EDGES + 255) / 256, 256, 0, stream>>>(dstp, cursor);
  k_scan<<<1, 1024, 0, stream>>>(cursor, indptr, cursor);
  k_scatter<<<(N_EDGES + 255) / 256, 256, 0, stream>>>(dstp, cursor, eid);

  // ---- GATv2 layers ----
  for (int l = 0; l < LAYERS; ++l){
    if (l == 0){
      k_xf0<<<(int)(NC / 256), 256, 0, stream>>>(x, Wl0, Wr0, xl, xr);
    } else {
      const float* xin = xs + (size_t)(l - 1) * NC;
      k_gemm<<<dim3(157, 2), 256, 0, stream>>>(
          xin, WlR + (size_t)(l - 1) * CH * CH, CH, 0,
          nullptr, nullptr, 0, 0, nullptr, nullptr, xl, N_NODES, CH);
      k_gemm<<<dim3(157, 2), 256, 0, stream>>>(
          xin, WrR + (size_t)(l - 1) * CH * CH, CH, 0,
          nullptr, nullptr, 0, 0, nullptr, nullptr, xr, N_NODES, CH);
    }
    const float* We  = (l == 0) ? We0  : WeR  + (size_t)(l - 1) * CH;
    const float* att = (l == 0) ? att0 : attR + (size_t)(l - 1) * CH;
    const float* bia = (l == 0) ? b0   : bR   + (size_t)(l - 1) * CH;
    k_edge<<<8192, 256, 0, stream>>>(srcp, dstp, ea, xl, xr, We, att, logit);
    k_segsm<<<5000, 256, 0, stream>>>(indptr, eid, logit);
    k_agg<<<N_NODES, 256, 0, stream>>>(indptr, eid, srcp, logit, xl, bia,
                                       xs + (size_t)l * NC);
  }

  // ---- LSTM forward (chunked over nodes; chunks are row-disjoint in h/c) ----
  hipMemsetAsync(hbuf, 0, 2 * NHf * sizeof(float), stream);
  for (int t = 0; t < LAYERS; t++){
    for (int c0 = 0; c0 < N_NODES; c0 += GC){
      int mm = (N_NODES - c0 < GC) ? (N_NODES - c0) : GC;
      k_gemm<<<dim3((mm + 127) / 128, 16), 256, 0, stream>>>(
          xs + (size_t)t * NC + (size_t)c0 * CH, Wih_f, CH, 1,
          hbuf + (size_t)c0 * HID, Whh_f, HID, 1,
          bih_f, bhh_f, gates, mm, G4);
      k_cell<<<mm, 512, 0, stream>>>(gates, hbuf + (size_t)c0 * HID,
                                     cbuf + (size_t)c0 * HID, jkw,
                                     scores + (size_t)t * N_NODES + c0, 0);
    }
  }
  // ---- LSTM backward ----
  hipMemsetAsync(hbuf, 0, 2 * NHf * sizeof(float), stream);
  for (int s = 0; s < LAYERS; s++){
    int t = LAYERS - 1 - s;
    for (int c0 = 0; c0 < N_NODES; c0 += GC){
      int mm = (N_NODES - c0 < GC) ? (N_NODES - c0) : GC;
      k_gemm<<<dim3((mm + 127) / 128, 16), 256, 0, stream>>>(
          xs + (size_t)t * NC + (size_t)c0 * CH, Wih_b, CH, 1,
          hbuf + (size_t)c0 * HID, Whh_b, HID, 1,
          bih_b, bhh_b, gates, mm, G4);
      k_cell<<<mm, 512, 0, stream>>>(gates, hbuf + (size_t)c0 * HID,
                                     cbuf + (size_t)c0 * HID, jkw + HID,
                                     scores + (size_t)t * N_NODES + c0, 1);
    }
  }

  // ---- JK combine + final norm ----
  k_jk<<<N_NODES, 256, 0, stream>>>(scores, xs, (float*)d_out);
  hipMemsetAsync(sums, 0, 512 * sizeof(float), stream);
  k_bnred<<<256, 256, 0, stream>>>((const float*)d_out, sums);
  k_bnapply<<<(int)(NC / 256), 256, 0, stream>>>((float*)d_out, sums, gamma, beta);
}

// Round 3
// 4041.396 us; speedup vs baseline: 4.2298x; 4.2298x over previous
//
#include <hip/hip_runtime.h>
#include <hip/hip_bf16.h>
#include <math.h>

#define N_NODES 20000
#define N_EDGES 640000
#define CH 256        // HEADS*DIM
#define LAYERS 4
#define HID 512
#define G4 2048       // 4*HID
#define EPS 1e-5f
#define SLOPE 0.2f

typedef __bf16 bf16x8 __attribute__((ext_vector_type(8)));
typedef float  f32x4  __attribute__((ext_vector_type(4)));

// ---------------- helpers ----------------
__device__ __forceinline__ float wave_red_sum(float v){
#pragma unroll
  for (int off = 32; off; off >>= 1) v += __shfl_xor(v, off, 64);
  return v;
}

// ---------------- CSR build ----------------
__global__ void k_hist(const int* __restrict__ dst, int* __restrict__ cnt){
  int e = blockIdx.x * 256 + threadIdx.x;
  if (e < N_EDGES) atomicAdd(&cnt[dst[e]], 1);
}

__global__ __launch_bounds__(1024) void k_scan(const int* __restrict__ cnt,
                                               int* __restrict__ indptr,
                                               int* __restrict__ cursor){
  __shared__ int buf[1024];
  __shared__ int carry;
  if (threadIdx.x == 0) carry = 0;
  __syncthreads();
  for (int base = 0; base < N_NODES; base += 1024){
    int i = base + threadIdx.x;
    int v = (i < N_NODES) ? cnt[i] : 0;
    buf[threadIdx.x] = v;
    __syncthreads();
#pragma unroll
    for (int off = 1; off < 1024; off <<= 1){
      int t = (threadIdx.x >= off) ? buf[threadIdx.x - off] : 0;
      __syncthreads();
      buf[threadIdx.x] += t;
      __syncthreads();
    }
    int excl = buf[threadIdx.x] - v;
    if (i < N_NODES){
      indptr[i] = carry + excl;
      cursor[i] = carry + excl;
    }
    __syncthreads();
    if (threadIdx.x == 0) carry += buf[1023];
    __syncthreads();
  }
  if (threadIdx.x == 0) indptr[N_NODES] = carry;
}

__global__ void k_scatter(const int* __restrict__ dst, int* __restrict__ cursor,
                          int* __restrict__ eid){
  int e = blockIdx.x * 256 + threadIdx.x;
  if (e < N_EDGES){
    int pos = atomicAdd(&cursor[dst[e]], 1);
    eid[pos] = e;
  }
}

// ---------------- f32 -> bf16 convert ----------------
__global__ void k_f2b(const float* __restrict__ src, __hip_bfloat16* __restrict__ dst,
                      int n){
  int i = blockIdx.x * 256 + threadIdx.x;
  if (i < n) dst[i] = __float2bfloat16(src[i]);
}

// ---------------- layer-0 transform (K=2) ----------------
__global__ void k_xf0(const float* __restrict__ x, const float* __restrict__ Wl,
                      const float* __restrict__ Wr, float* __restrict__ xl,
                      float* __restrict__ xr){
  int idx = blockIdx.x * 256 + threadIdx.x;
  int n = idx >> 8, cx = idx & 255;
  float x0 = x[n * 2], x1 = x[n * 2 + 1];
  xl[idx] = fmaf(x0, Wl[cx], x1 * Wl[CH + cx]);
  xr[idx] = fmaf(x0, Wr[cx], x1 * Wr[CH + cx]);
}

// ---------------- f32 GEMM (GAT transforms): C = A*B, B k-major [K][Nc] ----------------
__global__ __launch_bounds__(256) void k_gemm(
    const float* __restrict__ A, const float* __restrict__ B, int K,
    float* __restrict__ Cc, int M, int Nc)
{
  __shared__ float As[16][132];
  __shared__ float Bs[16][132];
  const int tid = threadIdx.x;
  const int tx = tid & 15, ty = tid >> 4;
  const int m0 = blockIdx.x * 128, n0 = blockIdx.y * 128;
  float acc[2][2][4][4];
#pragma unroll
  for (int a = 0; a < 2; a++)
#pragma unroll
    for (int b = 0; b < 2; b++)
#pragma unroll
      for (int i = 0; i < 4; i++)
#pragma unroll
        for (int j = 0; j < 4; j++) acc[a][b][i][j] = 0.f;

  for (int k0 = 0; k0 < K; k0 += 16){
#pragma unroll
    for (int i = 0; i < 8; i++){
      int id = tid + i * 256;
      int kk = id & 15, r = id >> 4;
      int m = m0 + r;
      As[kk][r] = (m < M) ? A[(size_t)m * K + (k0 + kk)] : 0.f;
    }
#pragma unroll
    for (int i = 0; i < 8; i++){
      int id = tid + i * 256;
      int j = id & 127, kk = id >> 7;
      Bs[kk][j] = B[(size_t)(k0 + kk) * Nc + (n0 + j)];
    }
    __syncthreads();
#pragma unroll
    for (int kk = 0; kk < 16; kk++){
      float4 a0 = *(const float4*)&As[kk][ty * 4];
      float4 a1 = *(const float4*)&As[kk][ty * 4 + 64];
      float4 b0 = *(const float4*)&Bs[kk][tx * 4];
      float4 b1 = *(const float4*)&Bs[kk][tx * 4 + 64];
      float av[2][4] = {{a0.x, a0.y, a0.z, a0.w}, {a1.x, a1.y, a1.z, a1.w}};
      float bv[2][4] = {{b0.x, b0.y, b0.z, b0.w}, {b1.x, b1.y, b1.z, b1.w}};
#pragma unroll
      for (int bi = 0; bi < 2; bi++)
#pragma unroll
        for (int i = 0; i < 4; i++)
#pragma unroll
          for (int bj = 0; bj < 2; bj++)
#pragma unroll
            for (int j = 0; j < 4; j++)
              acc[bi][bj][i][j] = fmaf(av[bi][i], bv[bj][j], acc[bi][bj][i][j]);
    }
    __syncthreads();
  }
#pragma unroll
  for (int bj = 0; bj < 2; bj++){
    int c0 = n0 + bj * 64 + tx * 4;
#pragma unroll
    for (int bi = 0; bi < 2; bi++)
#pragma unroll
      for (int i = 0; i < 4; i++){
        int m = m0 + bi * 64 + ty * 4 + i;
        if (m < M){
          float4 v = make_float4(acc[bi][bj][i][0], acc[bi][bj][i][1],
                                 acc[bi][bj][i][2], acc[bi][bj][i][3]);
          *(float4*)&Cc[(size_t)m * Nc + c0] = v;
        }
      }
  }
}

// ---------------- bf16 MFMA GEMM: C = [A1|A2] * [B1|B2]^T + bias1 + bias2 ----------------
// A1:[M][K1] bf16 (lda1=K1), A2:[M][K2] bf16; B1:[Nc][K1] bf16 n-major, B2:[Nc][K2]
// tile 128x128, BK=32, 4 waves (2x2 of 64x64), mfma_f32_16x16x32_bf16
__global__ __launch_bounds__(256) void k_gemm_bf(
    const __hip_bfloat16* __restrict__ A1, int K1,
    const __hip_bfloat16* __restrict__ A2, int K2,
    const __hip_bfloat16* __restrict__ B1, const __hip_bfloat16* __restrict__ B2,
    const float* __restrict__ bias1, const float* __restrict__ bias2,
    float* __restrict__ Cc, int M, int Nc)
{
  __shared__ __align__(16) unsigned short As[128 * 32];  // [m][k], 64B rows
  __shared__ __align__(16) unsigned short Bs[128 * 32];  // [n][k]
  const int tid = threadIdx.x;
  const int lane = tid & 63, w = tid >> 6;
  const int wr = w >> 1, wc = w & 1;
  const int m0 = blockIdx.x * 128, n0 = blockIdx.y * 128;
  const int l15 = lane & 15, l4 = lane >> 4;

  f32x4 acc[4][4];
#pragma unroll
  for (int i = 0; i < 4; i++)
#pragma unroll
    for (int j = 0; j < 4; j++) acc[i][j] = (f32x4){0.f, 0.f, 0.f, 0.f};

  const int nt1 = K1 / 32, nt2 = K2 / 32;
  const int smk = (tid & 3) * 8;          // staging k offset (8 bf16 = 16B)
  const int smr = tid >> 2;               // staging row 0..63 (+64 second pass)

  for (int kt = 0; kt < nt1 + nt2; ++kt){
    const __hip_bfloat16* Ab; const __hip_bfloat16* Bb; int K, k0;
    if (kt < nt1){ Ab = A1; Bb = B1; K = K1; k0 = kt * 32; }
    else         { Ab = A2; Bb = B2; K = K2; k0 = (kt - nt1) * 32; }
#pragma unroll
    for (int i = 0; i < 2; i++){
      int m = smr + i * 64;
      int gm = m0 + m;
      uint4 v = make_uint4(0u, 0u, 0u, 0u);
      if (gm < M) v = *(const uint4*)(Ab + (size_t)gm * K + k0 + smk);
      *(uint4*)&As[m * 32 + smk] = v;
    }
#pragma unroll
    for (int i = 0; i < 2; i++){
      int n = smr + i * 64;
      uint4 v = *(const uint4*)(Bb + (size_t)(n0 + n) * K + k0 + smk);
      *(uint4*)&Bs[n * 32 + smk] = v;
    }
    __syncthreads();
    bf16x8 af[4], bfr[4];
#pragma unroll
    for (int f = 0; f < 4; f++){
      af[f]  = *(const bf16x8*)&As[(wr * 64 + f * 16 + l15) * 32 + l4 * 8];
      bfr[f] = *(const bf16x8*)&Bs[(wc * 64 + f * 16 + l15) * 32 + l4 * 8];
    }
#pragma unroll
    for (int fi = 0; fi < 4; fi++)
#pragma unroll
      for (int fj = 0; fj < 4; fj++)
        acc[fi][fj] = __builtin_amdgcn_mfma_f32_16x16x32_bf16(af[fi], bfr[fj],
                                                              acc[fi][fj], 0, 0, 0);
    __syncthreads();
  }

  // epilogue: D col = lane&15, row = (lane>>4)*4 + reg   [m89]
#pragma unroll
  for (int fj = 0; fj < 4; fj++){
    int col = n0 + wc * 64 + fj * 16 + l15;
    float bb = 0.f;
    if (bias1) bb += bias1[col];
    if (bias2) bb += bias2[col];
#pragma unroll
    for (int fi = 0; fi < 4; fi++){
      int rbase = m0 + wr * 64 + fi * 16 + l4 * 4;
#pragma unroll
      for (int r = 0; r < 4; r++){
        int row = rbase + r;
        if (row < M) Cc[(size_t)row * Nc + col] = acc[fi][fj][r] + bb;
      }
    }
  }
}

// ---------------- edge logits: one wave per edge ----------------
__global__ __launch_bounds__(256) void k_edge(
    const int* __restrict__ src, const int* __restrict__ dst,
    const float* __restrict__ ea, const float* __restrict__ xl,
    const float* __restrict__ xr, const float* __restrict__ We,
    const float* __restrict__ att, float* __restrict__ logits)
{
  int gw = (blockIdx.x * 256 + threadIdx.x) >> 6;
  int lane = threadIdx.x & 63;
  int nw = (gridDim.x * 256) >> 6;
  for (int e = gw; e < N_EDGES; e += nw){
    int s = src[e], d = dst[e];
    float av = ea[e];
    float lg[4];
#pragma unroll
    for (int h = 0; h < 4; h++){
      int cc = h * 64 + lane;
      float v = xl[(size_t)s * CH + cc] + xr[(size_t)d * CH + cc] + av * We[cc];
      v = v > 0.f ? v : SLOPE * v;
      v *= att[cc];
      lg[h] = wave_red_sum(v);
    }
    if (lane == 0)
      *reinterpret_cast<float4*>(logits + (size_t)e * 4) =
          make_float4(lg[0], lg[1], lg[2], lg[3]);
  }
}

// ---------------- per-dst softmax (alpha in place) ----------------
__global__ __launch_bounds__(256) void k_segsm(const int* __restrict__ indptr,
                                               const int* __restrict__ eid,
                                               float* __restrict__ logits)
{
  int gw = (blockIdx.x * 256 + threadIdx.x) >> 6;
  int lane = threadIdx.x & 63;
  int nw = (gridDim.x * 256) >> 6;
  for (int n = gw; n < N_NODES; n += nw){
    int s0 = indptr[n], s1 = indptr[n + 1];
    float4 mx = make_float4(-1e30f, -1e30f, -1e30f, -1e30f);
    for (int i = s0 + lane; i < s1; i += 64){
      const float4 lg = *reinterpret_cast<const float4*>(logits + (size_t)eid[i] * 4);
      mx.x = fmaxf(mx.x, lg.x); mx.y = fmaxf(mx.y, lg.y);
      mx.z = fmaxf(mx.z, lg.z); mx.w = fmaxf(mx.w, lg.w);
    }
#pragma unroll
    for (int off = 32; off; off >>= 1){
      mx.x = fmaxf(mx.x, __shfl_xor(mx.x, off, 64));
      mx.y = fmaxf(mx.y, __shfl_xor(mx.y, off, 64));
      mx.z = fmaxf(mx.z, __shfl_xor(mx.z, off, 64));
      mx.w = fmaxf(mx.w, __shfl_xor(mx.w, off, 64));
    }
    float4 den = make_float4(0.f, 0.f, 0.f, 0.f);
    for (int i = s0 + lane; i < s1; i += 64){
      const float4 lg = *reinterpret_cast<const float4*>(logits + (size_t)eid[i] * 4);
      den.x += expf(lg.x - mx.x); den.y += expf(lg.y - mx.y);
      den.z += expf(lg.z - mx.z); den.w += expf(lg.w - mx.w);
    }
    den.x = wave_red_sum(den.x); den.y = wave_red_sum(den.y);
    den.z = wave_red_sum(den.z); den.w = wave_red_sum(den.w);
    float4 inv;
    inv.x = 1.f / den.x; inv.y = 1.f / den.y; inv.z = 1.f / den.z; inv.w = 1.f / den.w;
    for (int i = s0 + lane; i < s1; i += 64){
      float* p = logits + (size_t)eid[i] * 4;
      const float4 lg = *reinterpret_cast<const float4*>(p);
      *reinterpret_cast<float4*>(p) =
          make_float4(expf(lg.x - mx.x) * inv.x, expf(lg.y - mx.y) * inv.y,
                      expf(lg.z - mx.z) * inv.z, expf(lg.w - mx.w) * inv.w);
    }
  }
}

// ---------------- aggregate: block per dst node; writes f32 next-input + bf16 xs ----------------
__global__ __launch_bounds__(256) void k_agg(
    const int* __restrict__ indptr, const int* __restrict__ eid,
    const int* __restrict__ src, const float* __restrict__ alpha,
    const float* __restrict__ xl, const float* __restrict__ bias,
    float* __restrict__ xnext, __hip_bfloat16* __restrict__ xsb)
{
  int n = blockIdx.x;
  int t = threadIdx.x;
  int h = t >> 6;
  int s0 = indptr[n], s1 = indptr[n + 1];
  float acc = 0.f;
  for (int i = s0; i < s1; i++){
    int e = eid[i];
    int s = src[e];
    float a = alpha[(size_t)e * 4 + h];
    acc = fmaf(a, xl[(size_t)s * CH + t], acc);
  }
  float v = acc + bias[t];
  v = v > 0.f ? v : 0.f;                       // relu
  size_t idx = (size_t)n * CH + t;
  xnext[idx] = v;
  xsb[idx] = __float2bfloat16(v);
}

// ---------------- LSTM cell + JK score partial (h stored bf16) ----------------
__global__ __launch_bounds__(512) void k_cell(
    const float* __restrict__ gates, __hip_bfloat16* __restrict__ h,
    float* __restrict__ c, const float* __restrict__ jkw,
    float* __restrict__ score, int accum)
{
  int n = blockIdx.x, j = threadIdx.x;
  size_t gb = (size_t)n * G4;
  float gi = gates[gb + j];
  float gf = gates[gb + 512 + j];
  float gg = gates[gb + 1024 + j];
  float go = gates[gb + 1536 + j];
  size_t hb = (size_t)n * HID + j;
  float cv = c[hb];
  float iv = 1.f / (1.f + expf(-gi));
  float fv = 1.f / (1.f + expf(-gf));
  float ov = 1.f / (1.f + expf(-go));
  float cn = fv * cv + iv * tanhf(gg);
  float hn = ov * tanhf(cn);
  c[hb] = cn;
  h[hb] = __float2bfloat16(hn);
  float p = wave_red_sum(hn * jkw[j]);
  __shared__ float red[8];
  int lane = j & 63, wv = j >> 6;
  if (lane == 0) red[wv] = p;
  __syncthreads();
  if (j == 0){
    float tot = red[0] + red[1] + red[2] + red[3] + red[4] + red[5] + red[6] + red[7];
    if (accum) score[n] += tot; else score[n] = tot;
  }
}

// ---------------- JK softmax combine (xs in bf16) ----------------
__global__ __launch_bounds__(256) void k_jk(const float* __restrict__ scores,
                                            const __hip_bfloat16* __restrict__ xsb,
                                            float* __restrict__ out)
{
  int n = blockIdx.x, cx = threadIdx.x;
  float s0 = scores[n], s1 = scores[N_NODES + n];
  float s2 = scores[2 * N_NODES + n], s3 = scores[3 * N_NODES + n];
  float mx = fmaxf(fmaxf(s0, s1), fmaxf(s2, s3));
  float e0 = expf(s0 - mx), e1 = expf(s1 - mx), e2 = expf(s2 - mx), e3 = expf(s3 - mx);
  float inv = 1.f / (e0 + e1 + e2 + e3);
  size_t idx = (size_t)n * CH + cx;
  const size_t NC = (size_t)N_NODES * CH;
  float v = e0 * __bfloat162float(xsb[idx]) + e1 * __bfloat162float(xsb[NC + idx]) +
            e2 * __bfloat162float(xsb[2 * NC + idx]) + e3 * __bfloat162float(xsb[3 * NC + idx]);
  out[idx] = v * inv;
}

// ---------------- batch-norm style final ----------------
__global__ __launch_bounds__(256) void k_bnred(const float* __restrict__ out,
                                               float* __restrict__ sums)
{
  int cx = threadIdx.x;
  float s = 0.f, s2 = 0.f;
  for (int n = blockIdx.x; n < N_NODES; n += gridDim.x){
    float v = out[(size_t)n * CH + cx];
    s += v;
    s2 = fmaf(v, v, s2);
  }
  atomicAdd(&sums[cx], s);
  atomicAdd(&sums[CH + cx], s2);
}

__global__ __launch_bounds__(256) void k_bnapply(float* __restrict__ out,
                                                 const float* __restrict__ sums,
                                                 const float* __restrict__ gamma,
                                                 const float* __restrict__ beta)
{
  int idx = blockIdx.x * 256 + threadIdx.x;
  int cx = idx & 255;
  const float invN = 1.f / (float)N_NODES;
  float mean = sums[cx] * invN;
  float var = sums[CH + cx] * invN - mean * mean;
  out[idx] = (out[idx] - mean) * rsqrtf(var + EPS) * gamma[cx] + beta[cx];
}

// ---------------- host ----------------
extern "C" void kernel_launch(void* const* d_in, const int* in_sizes, int n_in,
                              void* d_out, int out_size, void* d_ws, size_t ws_size,
                              hipStream_t stream)
{
  const float* x     = (const float*)d_in[0];
  const int*   eidx  = (const int*)d_in[1];
  const int*   srcp  = eidx;
  const int*   dstp  = eidx + N_EDGES;
  const float* ea    = (const float*)d_in[2];
  const float* Wl0   = (const float*)d_in[3];
  const float* Wr0   = (const float*)d_in[4];
  const float* We0   = (const float*)d_in[5];
  const float* att0  = (const float*)d_in[6];
  const float* b0    = (const float*)d_in[7];
  const float* WlR   = (const float*)d_in[8];
  const float* WrR   = (const float*)d_in[9];
  const float* WeR   = (const float*)d_in[10];
  const float* attR  = (const float*)d_in[11];
  const float* bR    = (const float*)d_in[12];
  const float* Wih_f = (const float*)d_in[13];
  const float* Whh_f = (const float*)d_in[14];
  const float* bih_f = (const float*)d_in[15];
  const float* bhh_f = (const float*)d_in[16];
  const float* Wih_b = (const float*)d_in[17];
  const float* Whh_b = (const float*)d_in[18];
  const float* bih_b = (const float*)d_in[19];
  const float* bhh_b = (const float*)d_in[20];
  const float* jkw   = (const float*)d_in[21];
  const float* gamma = (const float*)d_in[23];
  const float* beta  = (const float*)d_in[24];

  // ---------- byte-precise workspace layout ----------
  char* base = (char*)d_ws;
  const size_t NC   = (size_t)N_NODES * CH;          // 5,120,000 elems
  const size_t NH   = (size_t)N_NODES * HID;         // 10,240,000 elems
  // persistent tail (weights bf16, scores, sums) at front
  size_t off = 0;
  __hip_bfloat16* wihf_b = (__hip_bfloat16*)(base + off); off += (size_t)G4 * CH * 2;   // 1,048,576
  __hip_bfloat16* whhf_b = (__hip_bfloat16*)(base + off); off += (size_t)G4 * HID * 2;  // 2,097,152
  __hip_bfloat16* wihb_b = (__hip_bfloat16*)(base + off); off += (size_t)G4 * CH * 2;
  __hip_bfloat16* whhb_b = (__hip_bfloat16*)(base + off); off += (size_t)G4 * HID * 2;
  float* scores = (float*)(base + off); off += (size_t)LAYERS * N_NODES * 4;            // 320,000
  float* sums   = (float*)(base + off); off += 2048;
  __hip_bfloat16* xsb = (__hip_bfloat16*)(base + off); off += LAYERS * NC * 2;          // 40,960,000
  const size_t R = off;                              // shared region base (~47.5 MB)
  // GAT view of R
  float* xin0  = (float*)(base + R);                 // ping  [N][CH] f32
  float* xin1  = xin0 + NC;                          // pong
  float* xl    = xin1 + NC;
  float* xr    = xl + NC;
  float* logit = xr + NC;                            // [E][4]
  int*   ibase = (int*)(logit + (size_t)N_EDGES * 4);
  int*   indptr = ibase;
  int*   cursor = ibase + (N_NODES + 1);
  int*   eid    = cursor + N_NODES;
  const size_t gat_end = R + (4 * NC + 4 * (size_t)N_EDGES) * 4
                       + (2 * (size_t)N_NODES + 1 + (size_t)N_EDGES) * 4;
  // LSTM view of R
  __hip_bfloat16* hbuf = (__hip_bfloat16*)(base + R); // [N][HID] bf16
  float* cbuf  = (float*)(base + R + NH * 2);         // [N][HID] f32
  float* gates = (float*)(base + R + NH * 2 + NH * 4);
  const size_t lstm_fixed = R + NH * 2 + NH * 4;

  if (gat_end > ws_size) return;                     // leave output poisoned
  long long gc_ll = ((long long)ws_size - (long long)lstm_fixed) / ((long long)G4 * 4);
  if (gc_ll > N_NODES) gc_ll = N_NODES;
  if (gc_ll < 128) return;
  const int GC = (int)gc_ll;

  // ---- CSR by dst ----
  hipMemsetAsync(cursor, 0, N_NODES * sizeof(int), stream);
  k_hist<<<(N_EDGES + 255) / 256, 256, 0, stream>>>(dstp, cursor);
  k_scan<<<1, 1024, 0, stream>>>(cursor, indptr, cursor);
  k_scatter<<<(N_EDGES + 255) / 256, 256, 0, stream>>>(dstp, cursor, eid);

  // ---- LSTM weight converts (done early; region disjoint from GAT scratch) ----
  k_f2b<<<((int)((size_t)G4 * CH) + 255) / 256, 256, 0, stream>>>(Wih_f, wihf_b, G4 * CH);
  k_f2b<<<((int)((size_t)G4 * HID) + 255) / 256, 256, 0, stream>>>(Whh_f, whhf_b, G4 * HID);
  k_f2b<<<((int)((size_t)G4 * CH) + 255) / 256, 256, 0, stream>>>(Wih_b, wihb_b, G4 * CH);
  k_f2b<<<((int)((size_t)G4 * HID) + 255) / 256, 256, 0, stream>>>(Whh_b, whhb_b, G4 * HID);

  // ---- GATv2 layers (f32 chain; xs stored bf16) ----
  float* ping = xin0; float* pong = xin1;
  for (int l = 0; l < LAYERS; ++l){
    if (l == 0){
      k_xf0<<<(int)(NC / 256), 256, 0, stream>>>(x, Wl0, Wr0, xl, xr);
    } else {
      k_gemm<<<dim3(157, 2), 256, 0, stream>>>(
          ping, WlR + (size_t)(l - 1) * CH * CH, CH, xl, N_NODES, CH);
      k_gemm<<<dim3(157, 2), 256, 0, stream>>>(
          ping, WrR + (size_t)(l - 1) * CH * CH, CH, xr, N_NODES, CH);
    }
    const float* We  = (l == 0) ? We0  : WeR  + (size_t)(l - 1) * CH;
    const float* att = (l == 0) ? att0 : attR + (size_t)(l - 1) * CH;
    const float* bia = (l == 0) ? b0   : bR   + (size_t)(l - 1) * CH;
    k_edge<<<8192, 256, 0, stream>>>(srcp, dstp, ea, xl, xr, We, att, logit);
    k_segsm<<<5000, 256, 0, stream>>>(indptr, eid, logit);
    k_agg<<<N_NODES, 256, 0, stream>>>(indptr, eid, srcp, logit, xl, bia,
                                       pong, xsb + (size_t)l * NC);
    float* tmp = ping; ping = pong; pong = tmp;
  }

  // ---- LSTM forward ----
  hipMemsetAsync(hbuf, 0, NH * 2, stream);
  hipMemsetAsync(cbuf, 0, NH * 4, stream);
  for (int t = 0; t < LAYERS; t++){
    for (int c0 = 0; c0 < N_NODES; c0 += GC){
      int mm = (N_NODES - c0 < GC) ? (N_NODES - c0) : GC;
      k_gemm_bf<<<dim3((mm + 127) / 128, G4 / 128), 256, 0, stream>>>(
          xsb + (size_t)t * NC + (size_t)c0 * CH, CH,
          hbuf + (size_t)c0 * HID, HID,
          wihf_b, whhf_b, bih_f, bhh_f, gates, mm, G4);
      k_cell<<<mm, 512, 0, stream>>>(gates, hbuf + (size_t)c0 * HID,
                                     cbuf + (size_t)c0 * HID, jkw,
                                     scores + (size_t)t * N_NODES + c0, 0);
    }
  }
  // ---- LSTM backward ----
  hipMemsetAsync(hbuf, 0, NH * 2, stream);
  hipMemsetAsync(cbuf, 0, NH * 4, stream);
  for (int s = 0; s < LAYERS; s++){
    int t = LAYERS - 1 - s;
    for (int c0 = 0; c0 < N_NODES; c0 += GC){
      int mm = (N_NODES - c0 < GC) ? (N_NODES - c0) : GC;
      k_gemm_bf<<<dim3((mm + 127) / 128, G4 / 128), 256, 0, stream>>>(
          xsb + (size_t)t * NC + (size_t)c0 * CH, CH,
          hbuf + (size_t)c0 * HID, HID,
          wihb_b, whhb_b, bih_b, bhh_b, gates, mm, G4);
      k_cell<<<mm, 512, 0, stream>>>(gates, hbuf + (size_t)c0 * HID,
                                     cbuf + (size_t)c0 * HID, jkw + HID,
                                     scores + (size_t)t * N_NODES + c0, 1);
    }
  }

  // ---- JK combine + final norm ----
  k_jk<<<N_NODES, 256, 0, stream>>>(scores, xsb, (float*)d_out);
  hipMemsetAsync(sums, 0, 2048, stream);
  k_bnred<<<256, 256, 0, stream>>>((const float*)d_out, sums);
  k_bnapply<<<(int)(NC / 256), 256, 0, stream>>>((float*)d_out, sums, gamma, beta);
}

// Round 4
// 3714.082 us; speedup vs baseline: 4.6026x; 1.0881x over previous
//
#include <hip/hip_runtime.h>
#include <hip/hip_bf16.h>
#include <math.h>

#define N_NODES 20000
#define N_EDGES 640000
#define CH 256        // HEADS*DIM
#define LAYERS 4
#define HID 512
#define G4 2048       // 4*HID
#define EPS 1e-5f
#define SLOPE 0.2f

typedef __bf16 bf16x8 __attribute__((ext_vector_type(8)));
typedef float  f32x4  __attribute__((ext_vector_type(4)));

// ---------------- helpers ----------------
__device__ __forceinline__ float wave_red_sum(float v){
#pragma unroll
  for (int off = 32; off; off >>= 1) v += __shfl_xor(v, off, 64);
  return v;
}

// async global->LDS, 16B per lane; lds dest = wave-uniform base + lane*16
__device__ __forceinline__ void gload16(const void* g, void* l){
  __builtin_amdgcn_global_load_lds(
      (const __attribute__((address_space(1))) void*)g,
      (__attribute__((address_space(3))) void*)l, 16, 0, 0);
}

// ---------------- CSR build ----------------
__global__ void k_hist(const int* __restrict__ dst, int* __restrict__ cnt){
  int e = blockIdx.x * 256 + threadIdx.x;
  if (e < N_EDGES) atomicAdd(&cnt[dst[e]], 1);
}

__global__ __launch_bounds__(1024) void k_scan(const int* __restrict__ cnt,
                                               int* __restrict__ indptr,
                                               int* __restrict__ cursor){
  __shared__ int buf[1024];
  __shared__ int carry;
  if (threadIdx.x == 0) carry = 0;
  __syncthreads();
  for (int base = 0; base < N_NODES; base += 1024){
    int i = base + threadIdx.x;
    int v = (i < N_NODES) ? cnt[i] : 0;
    buf[threadIdx.x] = v;
    __syncthreads();
#pragma unroll
    for (int off = 1; off < 1024; off <<= 1){
      int t = (threadIdx.x >= off) ? buf[threadIdx.x - off] : 0;
      __syncthreads();
      buf[threadIdx.x] += t;
      __syncthreads();
    }
    int excl = buf[threadIdx.x] - v;
    if (i < N_NODES){
      indptr[i] = carry + excl;
      cursor[i] = carry + excl;
    }
    __syncthreads();
    if (threadIdx.x == 0) carry += buf[1023];
    __syncthreads();
  }
  if (threadIdx.x == 0) indptr[N_NODES] = carry;
}

__global__ void k_scatter(const int* __restrict__ dst, int* __restrict__ cursor,
                          int* __restrict__ eid){
  int e = blockIdx.x * 256 + threadIdx.x;
  if (e < N_EDGES){
    int pos = atomicAdd(&cursor[dst[e]], 1);
    eid[pos] = e;
  }
}

// ---------------- f32 -> bf16 convert ----------------
__global__ void k_f2b(const float* __restrict__ src, __hip_bfloat16* __restrict__ dst,
                      int n){
  int i = blockIdx.x * 256 + threadIdx.x;
  if (i < n) dst[i] = __float2bfloat16(src[i]);
}

// ---------------- layer-0 transform (K=2) ----------------
__global__ void k_xf0(const float* __restrict__ x, const float* __restrict__ Wl,
                      const float* __restrict__ Wr, float* __restrict__ xl,
                      float* __restrict__ xr){
  int idx = blockIdx.x * 256 + threadIdx.x;
  int n = idx >> 8, cx = idx & 255;
  float x0 = x[n * 2], x1 = x[n * 2 + 1];
  xl[idx] = fmaf(x0, Wl[cx], x1 * Wl[CH + cx]);
  xr[idx] = fmaf(x0, Wr[cx], x1 * Wr[CH + cx]);
}

// ---------------- f32 GEMM (GAT transforms): C = A*B, B k-major [K][Nc] ----------------
__global__ __launch_bounds__(256) void k_gemm(
    const float* __restrict__ A, const float* __restrict__ B, int K,
    float* __restrict__ Cc, int M, int Nc)
{
  __shared__ float As[16][132];
  __shared__ float Bs[16][132];
  const int tid = threadIdx.x;
  const int tx = tid & 15, ty = tid >> 4;
  const int m0 = blockIdx.x * 128, n0 = blockIdx.y * 128;
  float acc[2][2][4][4];
#pragma unroll
  for (int a = 0; a < 2; a++)
#pragma unroll
    for (int b = 0; b < 2; b++)
#pragma unroll
      for (int i = 0; i < 4; i++)
#pragma unroll
        for (int j = 0; j < 4; j++) acc[a][b][i][j] = 0.f;

  for (int k0 = 0; k0 < K; k0 += 16){
#pragma unroll
    for (int i = 0; i < 8; i++){
      int id = tid + i * 256;
      int kk = id & 15, r = id >> 4;
      int m = m0 + r;
      As[kk][r] = (m < M) ? A[(size_t)m * K + (k0 + kk)] : 0.f;
    }
#pragma unroll
    for (int i = 0; i < 8; i++){
      int id = tid + i * 256;
      int j = id & 127, kk = id >> 7;
      Bs[kk][j] = B[(size_t)(k0 + kk) * Nc + (n0 + j)];
    }
    __syncthreads();
#pragma unroll
    for (int kk = 0; kk < 16; kk++){
      float4 a0 = *(const float4*)&As[kk][ty * 4];
      float4 a1 = *(const float4*)&As[kk][ty * 4 + 64];
      float4 b0 = *(const float4*)&Bs[kk][tx * 4];
      float4 b1 = *(const float4*)&Bs[kk][tx * 4 + 64];
      float av[2][4] = {{a0.x, a0.y, a0.z, a0.w}, {a1.x, a1.y, a1.z, a1.w}};
      float bv[2][4] = {{b0.x, b0.y, b0.z, b0.w}, {b1.x, b1.y, b1.z, b1.w}};
#pragma unroll
      for (int bi = 0; bi < 2; bi++)
#pragma unroll
        for (int i = 0; i < 4; i++)
#pragma unroll
          for (int bj = 0; bj < 2; bj++)
#pragma unroll
            for (int j = 0; j < 4; j++)
              acc[bi][bj][i][j] = fmaf(av[bi][i], bv[bj][j], acc[bi][bj][i][j]);
    }
    __syncthreads();
  }
#pragma unroll
  for (int bj = 0; bj < 2; bj++){
    int c0 = n0 + bj * 64 + tx * 4;
#pragma unroll
    for (int bi = 0; bi < 2; bi++)
#pragma unroll
      for (int i = 0; i < 4; i++){
        int m = m0 + bi * 64 + ty * 4 + i;
        if (m < M){
          float4 v = make_float4(acc[bi][bj][i][0], acc[bi][bj][i][1],
                                 acc[bi][bj][i][2], acc[bi][bj][i][3]);
          *(float4*)&Cc[(size_t)m * Nc + c0] = v;
        }
      }
  }
}

// ---------------- bf16 MFMA GEMM (m97 structure): C = [A1|A2]*[B1|B2]^T + bias ----------------
// A1:[M][K1] bf16, A2:[M][K2] bf16; B1:[Nc][K1], B2:[Nc][K2] (n-major weights)
// tile 128x128, BK=32, 4 waves (2x2 of 64x64), global_load_lds x16 staging.
// NOTE: tail tiles read up to 127 rows past M (stays inside d_ws; never written).
__global__ __launch_bounds__(256) void k_gemm_bf(
    const __hip_bfloat16* __restrict__ A1, int K1,
    const __hip_bfloat16* __restrict__ A2, int K2,
    const __hip_bfloat16* __restrict__ B1, const __hip_bfloat16* __restrict__ B2,
    const float* __restrict__ bias1, const float* __restrict__ bias2,
    __hip_bfloat16* __restrict__ Cc, int M, int Nc)
{
  __shared__ __align__(16) unsigned short As[128 * 32];  // [row][k], 64B rows
  __shared__ __align__(16) unsigned short Bs[128 * 32];  // [n][k]
  const int tid = threadIdx.x;
  const int lane = tid & 63, w = tid >> 6;
  const int wr = w >> 1, wc = w & 1;
  const int m0 = blockIdx.x * 128, n0 = blockIdx.y * 128;
  const int l15 = lane & 15, l4 = lane >> 4;
  const int srow = lane >> 2;          // staging row within 16-row group
  const int skk  = (lane & 3) * 8;     // staging k offset (8 bf16 = 16B)

  f32x4 acc[4][4];
#pragma unroll
  for (int i = 0; i < 4; i++)
#pragma unroll
    for (int j = 0; j < 4; j++) acc[i][j] = (f32x4){0.f, 0.f, 0.f, 0.f};

  const int nt1 = K1 / 32, nt2 = K2 / 32;

  for (int kt = 0; kt < nt1 + nt2; ++kt){
    const __hip_bfloat16* Ab; const __hip_bfloat16* Bb; int K, k0;
    if (kt < nt1){ Ab = A1; Bb = B1; K = K1; k0 = kt * 32; }
    else         { Ab = A2; Bb = B2; K = K2; k0 = (kt - nt1) * 32; }
    // each wave stages its 32 rows of A and of B via 2+2 global_load_lds x16
#pragma unroll
    for (int i = 0; i < 2; i++){
      int rbase = w * 32 + i * 16;
      int row = rbase + srow;
      gload16(Ab + (size_t)(m0 + row) * K + k0 + skk, &As[rbase * 32]);
      gload16(Bb + (size_t)(n0 + row) * K + k0 + skk, &Bs[rbase * 32]);
    }
    __syncthreads();   // compiler drains vmcnt before barrier
    bf16x8 af[4], bfr[4];
#pragma unroll
    for (int f = 0; f < 4; f++){
      af[f]  = *(const bf16x8*)&As[(wr * 64 + f * 16 + l15) * 32 + l4 * 8];
      bfr[f] = *(const bf16x8*)&Bs[(wc * 64 + f * 16 + l15) * 32 + l4 * 8];
    }
#pragma unroll
    for (int fi = 0; fi < 4; fi++)
#pragma unroll
      for (int fj = 0; fj < 4; fj++)
        acc[fi][fj] = __builtin_amdgcn_mfma_f32_16x16x32_bf16(af[fi], bfr[fj],
                                                              acc[fi][fj], 0, 0, 0);
    __syncthreads();
  }

  // epilogue: D col = lane&15, row = (lane>>4)*4 + reg  [m89]; gates out in bf16
#pragma unroll
  for (int fj = 0; fj < 4; fj++){
    int col = n0 + wc * 64 + fj * 16 + l15;
    float bb = 0.f;
    if (bias1) bb += bias1[col];
    if (bias2) bb += bias2[col];
#pragma unroll
    for (int fi = 0; fi < 4; fi++){
      int rbase = m0 + wr * 64 + fi * 16 + l4 * 4;
#pragma unroll
      for (int r = 0; r < 4; r++){
        int row = rbase + r;
        if (row < M)
          Cc[(size_t)row * Nc + col] = __float2bfloat16(acc[fi][fj][r] + bb);
      }
    }
  }
}

// ---------------- edge logits: one wave per edge ----------------
__global__ __launch_bounds__(256) void k_edge(
    const int* __restrict__ src, const int* __restrict__ dst,
    const float* __restrict__ ea, const float* __restrict__ xl,
    const float* __restrict__ xr, const float* __restrict__ We,
    const float* __restrict__ att, float* __restrict__ logits)
{
  int gw = (blockIdx.x * 256 + threadIdx.x) >> 6;
  int lane = threadIdx.x & 63;
  int nw = (gridDim.x * 256) >> 6;
  for (int e = gw; e < N_EDGES; e += nw){
    int s = src[e], d = dst[e];
    float av = ea[e];
    float lg[4];
#pragma unroll
    for (int h = 0; h < 4; h++){
      int cc = h * 64 + lane;
      float v = xl[(size_t)s * CH + cc] + xr[(size_t)d * CH + cc] + av * We[cc];
      v = v > 0.f ? v : SLOPE * v;
      v *= att[cc];
      lg[h] = wave_red_sum(v);
    }
    if (lane == 0)
      *reinterpret_cast<float4*>(logits + (size_t)e * 4) =
          make_float4(lg[0], lg[1], lg[2], lg[3]);
  }
}

// ---------------- per-dst softmax (alpha in place) ----------------
__global__ __launch_bounds__(256) void k_segsm(const int* __restrict__ indptr,
                                               const int* __restrict__ eid,
                                               float* __restrict__ logits)
{
  int gw = (blockIdx.x * 256 + threadIdx.x) >> 6;
  int lane = threadIdx.x & 63;
  int nw = (gridDim.x * 256) >> 6;
  for (int n = gw; n < N_NODES; n += nw){
    int s0 = indptr[n], s1 = indptr[n + 1];
    float4 mx = make_float4(-1e30f, -1e30f, -1e30f, -1e30f);
    for (int i = s0 + lane; i < s1; i += 64){
      const float4 lg = *reinterpret_cast<const float4*>(logits + (size_t)eid[i] * 4);
      mx.x = fmaxf(mx.x, lg.x); mx.y = fmaxf(mx.y, lg.y);
      mx.z = fmaxf(mx.z, lg.z); mx.w = fmaxf(mx.w, lg.w);
    }
#pragma unroll
    for (int off = 32; off; off >>= 1){
      mx.x = fmaxf(mx.x, __shfl_xor(mx.x, off, 64));
      mx.y = fmaxf(mx.y, __shfl_xor(mx.y, off, 64));
      mx.z = fmaxf(mx.z, __shfl_xor(mx.z, off, 64));
      mx.w = fmaxf(mx.w, __shfl_xor(mx.w, off, 64));
    }
    float4 den = make_float4(0.f, 0.f, 0.f, 0.f);
    for (int i = s0 + lane; i < s1; i += 64){
      const float4 lg = *reinterpret_cast<const float4*>(logits + (size_t)eid[i] * 4);
      den.x += expf(lg.x - mx.x); den.y += expf(lg.y - mx.y);
      den.z += expf(lg.z - mx.z); den.w += expf(lg.w - mx.w);
    }
    den.x = wave_red_sum(den.x); den.y = wave_red_sum(den.y);
    den.z = wave_red_sum(den.z); den.w = wave_red_sum(den.w);
    float4 inv;
    inv.x = 1.f / den.x; inv.y = 1.f / den.y; inv.z = 1.f / den.z; inv.w = 1.f / den.w;
    for (int i = s0 + lane; i < s1; i += 64){
      float* p = logits + (size_t)eid[i] * 4;
      const float4 lg = *reinterpret_cast<const float4*>(p);
      *reinterpret_cast<float4*>(p) =
          make_float4(expf(lg.x - mx.x) * inv.x, expf(lg.y - mx.y) * inv.y,
                      expf(lg.z - mx.z) * inv.z, expf(lg.w - mx.w) * inv.w);
    }
  }
}

// ---------------- aggregate: block per dst node; writes f32 next-input + bf16 xs ----------------
__global__ __launch_bounds__(256) void k_agg(
    const int* __restrict__ indptr, const int* __restrict__ eid,
    const int* __restrict__ src, const float* __restrict__ alpha,
    const float* __restrict__ xl, const float* __restrict__ bias,
    float* __restrict__ xnext, __hip_bfloat16* __restrict__ xsb)
{
  int n = blockIdx.x;
  int t = threadIdx.x;
  int h = t >> 6;
  int s0 = indptr[n], s1 = indptr[n + 1];
  float acc = 0.f;
  for (int i = s0; i < s1; i++){
    int e = eid[i];
    int s = src[e];
    float a = alpha[(size_t)e * 4 + h];
    acc = fmaf(a, xl[(size_t)s * CH + t], acc);
  }
  float v = acc + bias[t];
  v = v > 0.f ? v : 0.f;                       // relu
  size_t idx = (size_t)n * CH + t;
  xnext[idx] = v;
  xsb[idx] = __float2bfloat16(v);
}

// ---------------- LSTM cell + JK score partial (gates bf16, h bf16, c f32) ----------------
__global__ __launch_bounds__(512) void k_cell(
    const __hip_bfloat16* __restrict__ gates, __hip_bfloat16* __restrict__ h,
    float* __restrict__ c, const float* __restrict__ jkw,
    float* __restrict__ score, int accum)
{
  int n = blockIdx.x, j = threadIdx.x;
  size_t gb = (size_t)n * G4;
  float gi = __bfloat162float(gates[gb + j]);
  float gf = __bfloat162float(gates[gb + 512 + j]);
  float gg = __bfloat162float(gates[gb + 1024 + j]);
  float go = __bfloat162float(gates[gb + 1536 + j]);
  size_t hb = (size_t)n * HID + j;
  float cv = c[hb];
  float iv = 1.f / (1.f + expf(-gi));
  float fv = 1.f / (1.f + expf(-gf));
  float ov = 1.f / (1.f + expf(-go));
  float cn = fv * cv + iv * tanhf(gg);
  float hn = ov * tanhf(cn);
  c[hb] = cn;
  h[hb] = __float2bfloat16(hn);
  float p = wave_red_sum(hn * jkw[j]);
  __shared__ float red[8];
  int lane = j & 63, wv = j >> 6;
  if (lane == 0) red[wv] = p;
  __syncthreads();
  if (j == 0){
    float tot = red[0] + red[1] + red[2] + red[3] + red[4] + red[5] + red[6] + red[7];
    if (accum) score[n] += tot; else score[n] = tot;
  }
}

// ---------------- JK softmax combine (xs in bf16) ----------------
__global__ __launch_bounds__(256) void k_jk(const float* __restrict__ scores,
                                            const __hip_bfloat16* __restrict__ xsb,
                                            float* __restrict__ out)
{
  int n = blockIdx.x, cx = threadIdx.x;
  float s0 = scores[n], s1 = scores[N_NODES + n];
  float s2 = scores[2 * N_NODES + n], s3 = scores[3 * N_NODES + n];
  float mx = fmaxf(fmaxf(s0, s1), fmaxf(s2, s3));
  float e0 = expf(s0 - mx), e1 = expf(s1 - mx), e2 = expf(s2 - mx), e3 = expf(s3 - mx);
  float inv = 1.f / (e0 + e1 + e2 + e3);
  size_t idx = (size_t)n * CH + cx;
  const size_t NC = (size_t)N_NODES * CH;
  float v = e0 * __bfloat162float(xsb[idx]) + e1 * __bfloat162float(xsb[NC + idx]) +
            e2 * __bfloat162float(xsb[2 * NC + idx]) + e3 * __bfloat162float(xsb[3 * NC + idx]);
  out[idx] = v * inv;
}

// ---------------- batch-norm style final ----------------
__global__ __launch_bounds__(256) void k_bnred(const float* __restrict__ out,
                                               float* __restrict__ sums)
{
  int cx = threadIdx.x;
  float s = 0.f, s2 = 0.f;
  for (int n = blockIdx.x; n < N_NODES; n += gridDim.x){
    float v = out[(size_t)n * CH + cx];
    s += v;
    s2 = fmaf(v, v, s2);
  }
  atomicAdd(&sums[cx], s);
  atomicAdd(&sums[CH + cx], s2);
}

__global__ __launch_bounds__(256) void k_bnapply(float* __restrict__ out,
                                                 const float* __restrict__ sums,
                                                 const float* __restrict__ gamma,
                                                 const float* __restrict__ beta)
{
  int idx = blockIdx.x * 256 + threadIdx.x;
  int cx = idx & 255;
  const float invN = 1.f / (float)N_NODES;
  float mean = sums[cx] * invN;
  float var = sums[CH + cx] * invN - mean * mean;
  out[idx] = (out[idx] - mean) * rsqrtf(var + EPS) * gamma[cx] + beta[cx];
}

// ---------------- host ----------------
extern "C" void kernel_launch(void* const* d_in, const int* in_sizes, int n_in,
                              void* d_out, int out_size, void* d_ws, size_t ws_size,
                              hipStream_t stream)
{
  const float* x     = (const float*)d_in[0];
  const int*   eidx  = (const int*)d_in[1];
  const int*   srcp  = eidx;
  const int*   dstp  = eidx + N_EDGES;
  const float* ea    = (const float*)d_in[2];
  const float* Wl0   = (const float*)d_in[3];
  const float* Wr0   = (const float*)d_in[4];
  const float* We0   = (const float*)d_in[5];
  const float* att0  = (const float*)d_in[6];
  const float* b0    = (const float*)d_in[7];
  const float* WlR   = (const float*)d_in[8];
  const float* WrR   = (const float*)d_in[9];
  const float* WeR   = (const float*)d_in[10];
  const float* attR  = (const float*)d_in[11];
  const float* bR    = (const float*)d_in[12];
  const float* Wih_f = (const float*)d_in[13];
  const float* Whh_f = (const float*)d_in[14];
  const float* bih_f = (const float*)d_in[15];
  const float* bhh_f = (const float*)d_in[16];
  const float* Wih_b = (const float*)d_in[17];
  const float* Whh_b = (const float*)d_in[18];
  const float* bih_b = (const float*)d_in[19];
  const float* bhh_b = (const float*)d_in[20];
  const float* jkw   = (const float*)d_in[21];
  const float* gamma = (const float*)d_in[23];
  const float* beta  = (const float*)d_in[24];

  // ---------- byte-precise workspace layout ----------
  char* base = (char*)d_ws;
  const size_t NC   = (size_t)N_NODES * CH;          // 5,120,000 elems
  const size_t NH   = (size_t)N_NODES * HID;         // 10,240,000 elems
  size_t off = 0;
  __hip_bfloat16* wihf_b = (__hip_bfloat16*)(base + off); off += (size_t)G4 * CH * 2;
  __hip_bfloat16* whhf_b = (__hip_bfloat16*)(base + off); off += (size_t)G4 * HID * 2;
  __hip_bfloat16* wihb_b = (__hip_bfloat16*)(base + off); off += (size_t)G4 * CH * 2;
  __hip_bfloat16* whhb_b = (__hip_bfloat16*)(base + off); off += (size_t)G4 * HID * 2;
  float* scores = (float*)(base + off); off += (size_t)LAYERS * N_NODES * 4;
  float* sums   = (float*)(base + off); off += 2048;
  __hip_bfloat16* xsb = (__hip_bfloat16*)(base + off); off += LAYERS * NC * 2;
  const size_t R = off;                              // shared region base (~47.5 MB)
  // GAT view of R
  float* xin0  = (float*)(base + R);                 // ping  [N][CH] f32
  float* xin1  = xin0 + NC;                          // pong
  float* xl    = xin1 + NC;
  float* xr    = xl + NC;
  float* logit = xr + NC;                            // [E][4]
  int*   ibase = (int*)(logit + (size_t)N_EDGES * 4);
  int*   indptr = ibase;
  int*   cursor = ibase + (N_NODES + 1);
  int*   eid    = cursor + N_NODES;
  const size_t gat_end = R + (4 * NC + 4 * (size_t)N_EDGES) * 4
                       + (2 * (size_t)N_NODES + 1 + (size_t)N_EDGES) * 4;
  // LSTM view of R
  __hip_bfloat16* hbuf = (__hip_bfloat16*)(base + R); // [N][HID] bf16
  float* cbuf  = (float*)(base + R + NH * 2);         // [N][HID] f32
  __hip_bfloat16* gates = (__hip_bfloat16*)(base + R + NH * 2 + NH * 4);
  const size_t lstm_fixed = R + NH * 2 + NH * 4;

  if (gat_end > ws_size) return;                     // leave output poisoned
  long long gc_ll = ((long long)ws_size - (long long)lstm_fixed) / ((long long)G4 * 2);
  if (gc_ll > N_NODES) gc_ll = N_NODES;
  if (gc_ll < 128) return;
  const int GC = (int)(gc_ll & ~127LL);              // multiple of 128 tiles

  // ---- CSR by dst ----
  hipMemsetAsync(cursor, 0, N_NODES * sizeof(int), stream);
  k_hist<<<(N_EDGES + 255) / 256, 256, 0, stream>>>(dstp, cursor);
  k_scan<<<1, 1024, 0, stream>>>(cursor, indptr, cursor);
  k_scatter<<<(N_EDGES + 255) / 256, 256, 0, stream>>>(dstp, cursor, eid);

  // ---- LSTM weight converts ----
  k_f2b<<<((int)((size_t)G4 * CH) + 255) / 256, 256, 0, stream>>>(Wih_f, wihf_b, G4 * CH);
  k_f2b<<<((int)((size_t)G4 * HID) + 255) / 256, 256, 0, stream>>>(Whh_f, whhf_b, G4 * HID);
  k_f2b<<<((int)((size_t)G4 * CH) + 255) / 256, 256, 0, stream>>>(Wih_b, wihb_b, G4 * CH);
  k_f2b<<<((int)((size_t)G4 * HID) + 255) / 256, 256, 0, stream>>>(Whh_b, whhb_b, G4 * HID);

  // ---- GATv2 layers (f32 chain; xs stored bf16) ----
  float* ping = xin0; float* pong = xin1;
  for (int l = 0; l < LAYERS; ++l){
    if (l == 0){
      k_xf0<<<(int)(NC / 256), 256, 0, stream>>>(x, Wl0, Wr0, xl, xr);
    } else {
      k_gemm<<<dim3(157, 2), 256, 0, stream>>>(
          ping, WlR + (size_t)(l - 1) * CH * CH, CH, xl, N_NODES, CH);
      k_gemm<<<dim3(157, 2), 256, 0, stream>>>(
          ping, WrR + (size_t)(l - 1) * CH * CH, CH, xr, N_NODES, CH);
    }
    const float* We  = (l == 0) ? We0  : WeR  + (size_t)(l - 1) * CH;
    const float* att = (l == 0) ? att0 : attR + (size_t)(l - 1) * CH;
    const float* bia = (l == 0) ? b0   : bR   + (size_t)(l - 1) * CH;
    k_edge<<<8192, 256, 0, stream>>>(srcp, dstp, ea, xl, xr, We, att, logit);
    k_segsm<<<5000, 256, 0, stream>>>(indptr, eid, logit);
    k_agg<<<N_NODES, 256, 0, stream>>>(indptr, eid, srcp, logit, xl, bia,
                                       pong, xsb + (size_t)l * NC);
    float* tmp = ping; ping = pong; pong = tmp;
  }

  // ---- LSTM forward ----
  hipMemsetAsync(hbuf, 0, NH * 2, stream);
  hipMemsetAsync(cbuf, 0, NH * 4, stream);
  for (int t = 0; t < LAYERS; t++){
    for (int c0 = 0; c0 < N_NODES; c0 += GC){
      int mm = (N_NODES - c0 < GC) ? (N_NODES - c0) : GC;
      k_gemm_bf<<<dim3((mm + 127) / 128, G4 / 128), 256, 0, stream>>>(
          xsb + (size_t)t * NC + (size_t)c0 * CH, CH,
          hbuf + (size_t)c0 * HID, HID,
          wihf_b, whhf_b, bih_f, bhh_f, gates, mm, G4);
      k_cell<<<mm, 512, 0, stream>>>(gates, hbuf + (size_t)c0 * HID,
                                     cbuf + (size_t)c0 * HID, jkw,
                                     scores + (size_t)t * N_NODES + c0, 0);
    }
  }
  // ---- LSTM backward ----
  hipMemsetAsync(hbuf, 0, NH * 2, stream);
  hipMemsetAsync(cbuf, 0, NH * 4, stream);
  for (int s = 0; s < LAYERS; s++){
    int t = LAYERS - 1 - s;
    for (int c0 = 0; c0 < N_NODES; c0 += GC){
      int mm = (N_NODES - c0 < GC) ? (N_NODES - c0) : GC;
      k_gemm_bf<<<dim3((mm + 127) / 128, G4 / 128), 256, 0, stream>>>(
          xsb + (size_t)t * NC + (size_t)c0 * CH, CH,
          hbuf + (size_t)c0 * HID, HID,
          wihb_b, whhb_b, bih_b, bhh_b, gates, mm, G4);
      k_cell<<<mm, 512, 0, stream>>>(gates, hbuf + (size_t)c0 * HID,
                                     cbuf + (size_t)c0 * HID, jkw + HID,
                                     scores + (size_t)t * N_NODES + c0, 1);
    }
  }

  // ---- JK combine + final norm ----
  k_jk<<<N_NODES, 256, 0, stream>>>(scores, xsb, (float*)d_out);
  hipMemsetAsync(sums, 0, 2048, stream);
  k_bnred<<<256, 256, 0, stream>>>((const float*)d_out, sums);
  k_bnapply<<<(int)(NC / 256), 256, 0, stream>>>((float*)d_out, sums, gamma, beta);
}

// Round 5
// 2502.727 us; speedup vs baseline: 6.8303x; 1.4840x over previous
//
#include <hip/hip_runtime.h>
#include <hip/hip_bf16.h>
#include <math.h>

#define N_NODES 20000
#define N_EDGES 640000
#define CH 256        // HEADS*DIM
#define LAYERS 4
#define HID 512
#define G4 2048       // 4*HID
#define EPS 1e-5f
#define SLOPE 0.2f

typedef __bf16 bf16x8 __attribute__((ext_vector_type(8)));
typedef float  f32x4  __attribute__((ext_vector_type(4)));

// ---------------- helpers ----------------
__device__ __forceinline__ float wave_red_sum(float v){
#pragma unroll
  for (int off = 32; off; off >>= 1) v += __shfl_xor(v, off, 64);
  return v;
}

// async global->LDS, 16B per lane; lds dest = wave-uniform base + lane*16
__device__ __forceinline__ void gload16(const void* g, void* l){
  __builtin_amdgcn_global_load_lds(
      (const __attribute__((address_space(1))) void*)g,
      (__attribute__((address_space(3))) void*)l, 16, 0, 0);
}

// bf16 pair -> float2 (bf16->f32 is a 16-bit shift)
__device__ __forceinline__ float2 ldbf2(const __hip_bfloat16* p){
  unsigned u = *(const unsigned*)p;
  float2 r;
  r.x = __uint_as_float(u << 16);
  r.y = __uint_as_float(u & 0xffff0000u);
  return r;
}

// ---------------- CSR build ----------------
__global__ void k_hist(const int* __restrict__ dst, int* __restrict__ cnt){
  int e = blockIdx.x * 256 + threadIdx.x;
  if (e < N_EDGES) atomicAdd(&cnt[dst[e]], 1);
}

__global__ __launch_bounds__(1024) void k_scan(const int* __restrict__ cnt,
                                               int* __restrict__ indptr,
                                               int* __restrict__ cursor){
  __shared__ int buf[1024];
  __shared__ int carry;
  if (threadIdx.x == 0) carry = 0;
  __syncthreads();
  for (int base = 0; base < N_NODES; base += 1024){
    int i = base + threadIdx.x;
    int v = (i < N_NODES) ? cnt[i] : 0;
    buf[threadIdx.x] = v;
    __syncthreads();
#pragma unroll
    for (int off = 1; off < 1024; off <<= 1){
      int t = (threadIdx.x >= off) ? buf[threadIdx.x - off] : 0;
      __syncthreads();
      buf[threadIdx.x] += t;
      __syncthreads();
    }
    int excl = buf[threadIdx.x] - v;
    if (i < N_NODES){
      indptr[i] = carry + excl;
      cursor[i] = carry + excl;
    }
    __syncthreads();
    if (threadIdx.x == 0) carry += buf[1023];
    __syncthreads();
  }
  if (threadIdx.x == 0) indptr[N_NODES] = carry;
}

// scatter src + edge_attr into dst-sorted order (no eid indirection later)
__global__ void k_scatter(const int* __restrict__ src, const int* __restrict__ dst,
                          const float* __restrict__ ea, int* __restrict__ cursor,
                          int* __restrict__ esrc, float* __restrict__ eea){
  int e = blockIdx.x * 256 + threadIdx.x;
  if (e < N_EDGES){
    int pos = atomicAdd(&cursor[dst[e]], 1);
    esrc[pos] = src[e];
    eea[pos] = ea[e];
  }
}

// ---------------- f32 -> bf16 convert ----------------
__global__ void k_f2b(const float* __restrict__ src, __hip_bfloat16* __restrict__ dst,
                      int n){
  int i = blockIdx.x * 256 + threadIdx.x;
  if (i < n) dst[i] = __float2bfloat16(src[i]);
}

// ---------------- layer-0 transform (K=2) ----------------
__global__ void k_xf0(const float* __restrict__ x, const float* __restrict__ Wl,
                      const float* __restrict__ Wr, float* __restrict__ xl,
                      float* __restrict__ xr){
  int idx = blockIdx.x * 256 + threadIdx.x;
  int n = idx >> 8, cx = idx & 255;
  float x0 = x[n * 2], x1 = x[n * 2 + 1];
  xl[idx] = fmaf(x0, Wl[cx], x1 * Wl[CH + cx]);
  xr[idx] = fmaf(x0, Wr[cx], x1 * Wr[CH + cx]);
}

// ---------------- f32 GEMM (GAT transforms): C = A*B, B k-major [K][Nc] ----------------
__global__ __launch_bounds__(256) void k_gemm(
    const float* __restrict__ A, const float* __restrict__ B, int K,
    float* __restrict__ Cc, int M, int Nc)
{
  __shared__ float As[16][132];
  __shared__ float Bs[16][132];
  const int tid = threadIdx.x;
  const int tx = tid & 15, ty = tid >> 4;
  const int m0 = blockIdx.x * 128, n0 = blockIdx.y * 128;
  float acc[2][2][4][4];
#pragma unroll
  for (int a = 0; a < 2; a++)
#pragma unroll
    for (int b = 0; b < 2; b++)
#pragma unroll
      for (int i = 0; i < 4; i++)
#pragma unroll
        for (int j = 0; j < 4; j++) acc[a][b][i][j] = 0.f;

  for (int k0 = 0; k0 < K; k0 += 16){
#pragma unroll
    for (int i = 0; i < 8; i++){
      int id = tid + i * 256;
      int kk = id & 15, r = id >> 4;
      int m = m0 + r;
      As[kk][r] = (m < M) ? A[(size_t)m * K + (k0 + kk)] : 0.f;
    }
#pragma unroll
    for (int i = 0; i < 8; i++){
      int id = tid + i * 256;
      int j = id & 127, kk = id >> 7;
      Bs[kk][j] = B[(size_t)(k0 + kk) * Nc + (n0 + j)];
    }
    __syncthreads();
#pragma unroll
    for (int kk = 0; kk < 16; kk++){
      float4 a0 = *(const float4*)&As[kk][ty * 4];
      float4 a1 = *(const float4*)&As[kk][ty * 4 + 64];
      float4 b0 = *(const float4*)&Bs[kk][tx * 4];
      float4 b1 = *(const float4*)&Bs[kk][tx * 4 + 64];
      float av[2][4] = {{a0.x, a0.y, a0.z, a0.w}, {a1.x, a1.y, a1.z, a1.w}};
      float bv[2][4] = {{b0.x, b0.y, b0.z, b0.w}, {b1.x, b1.y, b1.z, b1.w}};
#pragma unroll
      for (int bi = 0; bi < 2; bi++)
#pragma unroll
        for (int i = 0; i < 4; i++)
#pragma unroll
          for (int bj = 0; bj < 2; bj++)
#pragma unroll
            for (int j = 0; j < 4; j++)
              acc[bi][bj][i][j] = fmaf(av[bi][i], bv[bj][j], acc[bi][bj][i][j]);
    }
    __syncthreads();
  }
#pragma unroll
  for (int bj = 0; bj < 2; bj++){
    int c0 = n0 + bj * 64 + tx * 4;
#pragma unroll
    for (int bi = 0; bi < 2; bi++)
#pragma unroll
      for (int i = 0; i < 4; i++){
        int m = m0 + bi * 64 + ty * 4 + i;
        if (m < M){
          float4 v = make_float4(acc[bi][bj][i][0], acc[bi][bj][i][1],
                                 acc[bi][bj][i][2], acc[bi][bj][i][3]);
          *(float4*)&Cc[(size_t)m * Nc + c0] = v;
        }
      }
  }
}

// ---------------- bf16 MFMA GEMM (m97 structure): C = [A1|A2]*[B1|B2]^T + bias ----------------
__global__ __launch_bounds__(256) void k_gemm_bf(
    const __hip_bfloat16* __restrict__ A1, int K1,
    const __hip_bfloat16* __restrict__ A2, int K2,
    const __hip_bfloat16* __restrict__ B1, const __hip_bfloat16* __restrict__ B2,
    const float* __restrict__ bias1, const float* __restrict__ bias2,
    __hip_bfloat16* __restrict__ Cc, int M, int Nc)
{
  __shared__ __align__(16) unsigned short As[128 * 32];  // [row][k], 64B rows
  __shared__ __align__(16) unsigned short Bs[128 * 32];  // [n][k]
  const int tid = threadIdx.x;
  const int lane = tid & 63, w = tid >> 6;
  const int wr = w >> 1, wc = w & 1;
  const int m0 = blockIdx.x * 128, n0 = blockIdx.y * 128;
  const int l15 = lane & 15, l4 = lane >> 4;
  const int srow = lane >> 2;          // staging row within 16-row group
  const int skk  = (lane & 3) * 8;     // staging k offset (8 bf16 = 16B)

  f32x4 acc[4][4];
#pragma unroll
  for (int i = 0; i < 4; i++)
#pragma unroll
    for (int j = 0; j < 4; j++) acc[i][j] = (f32x4){0.f, 0.f, 0.f, 0.f};

  const int nt1 = K1 / 32, nt2 = K2 / 32;

  for (int kt = 0; kt < nt1 + nt2; ++kt){
    const __hip_bfloat16* Ab; const __hip_bfloat16* Bb; int K, k0;
    if (kt < nt1){ Ab = A1; Bb = B1; K = K1; k0 = kt * 32; }
    else         { Ab = A2; Bb = B2; K = K2; k0 = (kt - nt1) * 32; }
#pragma unroll
    for (int i = 0; i < 2; i++){
      int rbase = w * 32 + i * 16;
      int row = rbase + srow;
      gload16(Ab + (size_t)(m0 + row) * K + k0 + skk, &As[rbase * 32]);
      gload16(Bb + (size_t)(n0 + row) * K + k0 + skk, &Bs[rbase * 32]);
    }
    __syncthreads();
    bf16x8 af[4], bfr[4];
#pragma unroll
    for (int f = 0; f < 4; f++){
      af[f]  = *(const bf16x8*)&As[(wr * 64 + f * 16 + l15) * 32 + l4 * 8];
      bfr[f] = *(const bf16x8*)&Bs[(wc * 64 + f * 16 + l15) * 32 + l4 * 8];
    }
#pragma unroll
    for (int fi = 0; fi < 4; fi++)
#pragma unroll
      for (int fj = 0; fj < 4; fj++)
        acc[fi][fj] = __builtin_amdgcn_mfma_f32_16x16x32_bf16(af[fi], bfr[fj],
                                                              acc[fi][fj], 0, 0, 0);
    __syncthreads();
  }

  // epilogue: D col = lane&15, row = (lane>>4)*4 + reg  [m89]
#pragma unroll
  for (int fj = 0; fj < 4; fj++){
    int col = n0 + wc * 64 + fj * 16 + l15;
    float bb = 0.f;
    if (bias1) bb += bias1[col];
    if (bias2) bb += bias2[col];
#pragma unroll
    for (int fi = 0; fi < 4; fi++){
      int rbase = m0 + wr * 64 + fi * 16 + l4 * 4;
#pragma unroll
      for (int r = 0; r < 4; r++){
        int row = rbase + r;
        if (row < M)
          Cc[(size_t)row * Nc + col] = __float2bfloat16(acc[fi][fj][r] + bb);
      }
    }
  }
}

// ---------------- fused GAT message pass: per-dst online-softmax + aggregate ----------------
// block = dst node (256 threads, thread = channel, wave = head). Single pass over
// incoming edges: logit -> online softmax (m,l) -> weighted accumulation of xl[src].
__global__ __launch_bounds__(256) void k_gat(
    const int* __restrict__ indptr, const int* __restrict__ esrc,
    const float* __restrict__ eea, const float* __restrict__ xl,
    const float* __restrict__ xr, const float* __restrict__ We,
    const float* __restrict__ att, const float* __restrict__ bias,
    float* __restrict__ xnext, __hip_bfloat16* __restrict__ xsb)
{
  const int n = blockIdx.x;
  const int t = threadIdx.x;          // channel; wave (t>>6) = head
  const int s0 = indptr[n], s1 = indptr[n + 1];
  const float xr_t  = xr[(size_t)n * CH + t];
  const float We_t  = We[t];
  const float att_t = att[t];
  float m = -1e30f, l = 0.f, acc = 0.f;

  int i = s0;
  for (; i + 1 < s1; i += 2){         // 2-way unroll: both gathers in flight
    int   sA = esrc[i],  sB = esrc[i + 1];
    float aA = eea[i],   aB = eea[i + 1];
    float xvA = xl[(size_t)sA * CH + t];
    float xvB = xl[(size_t)sB * CH + t];
    float vA = xvA + xr_t + aA * We_t;
    vA = vA > 0.f ? vA : SLOPE * vA;
    float lgA = wave_red_sum(vA * att_t);
    float vB = xvB + xr_t + aB * We_t;
    vB = vB > 0.f ? vB : SLOPE * vB;
    float lgB = wave_red_sum(vB * att_t);
    float mn = fmaxf(m, lgA);
    float sc = __expf(m - mn), wA = __expf(lgA - mn);
    l = l * sc + wA;  acc = acc * sc + wA * xvA;  m = mn;
    mn = fmaxf(m, lgB);
    sc = __expf(m - mn); float wB = __expf(lgB - mn);
    l = l * sc + wB;  acc = acc * sc + wB * xvB;  m = mn;
  }
  if (i < s1){
    int   sA = esrc[i];
    float aA = eea[i];
    float xvA = xl[(size_t)sA * CH + t];
    float vA = xvA + xr_t + aA * We_t;
    vA = vA > 0.f ? vA : SLOPE * vA;
    float lgA = wave_red_sum(vA * att_t);
    float mn = fmaxf(m, lgA);
    float sc = __expf(m - mn), wA = __expf(lgA - mn);
    l = l * sc + wA;  acc = acc * sc + wA * xvA;  m = mn;
  }
  float invl = (l > 0.f) ? 1.f / l : 0.f;   // zero-in-degree guard
  float v = acc * invl + bias[t];
  v = v > 0.f ? v : 0.f;                    // relu
  size_t idx = (size_t)n * CH + t;
  xnext[idx] = v;
  xsb[idx] = __float2bfloat16(v);
}

// ---------------- LSTM cell + JK score partial (256 thr x 2 ch, vectorized) ----------------
__global__ __launch_bounds__(256) void k_cell(
    const __hip_bfloat16* __restrict__ gates, __hip_bfloat16* __restrict__ h,
    float* __restrict__ c, const float* __restrict__ jkw,
    float* __restrict__ score, int accum, int first)
{
  const int n = blockIdx.x;
  const int j = threadIdx.x * 2;            // channels j, j+1
  const size_t gb = (size_t)n * G4;
  float2 gi = ldbf2(gates + gb + j);
  float2 gf = ldbf2(gates + gb + 512 + j);
  float2 gg = ldbf2(gates + gb + 1024 + j);
  float2 go = ldbf2(gates + gb + 1536 + j);
  const size_t hb = (size_t)n * HID + j;
  float2 cv = first ? make_float2(0.f, 0.f) : *(const float2*)&c[hb];
  float ix = 1.f / (1.f + __expf(-gi.x)), iy = 1.f / (1.f + __expf(-gi.y));
  float fx = 1.f / (1.f + __expf(-gf.x)), fy = 1.f / (1.f + __expf(-gf.y));
  float ox = 1.f / (1.f + __expf(-go.x)), oy = 1.f / (1.f + __expf(-go.y));
  float cx = fx * cv.x + ix * tanhf(gg.x);
  float cy = fy * cv.y + iy * tanhf(gg.y);
  float hx = ox * tanhf(cx);
  float hy = oy * tanhf(cy);
  *(float2*)&c[hb] = make_float2(cx, cy);
  ushort2 hp;
  hp.x = __bfloat16_as_ushort(__float2bfloat16(hx));
  hp.y = __bfloat16_as_ushort(__float2bfloat16(hy));
  *(ushort2*)&h[hb] = hp;
  float2 jw = *(const float2*)&jkw[j];
  float p = wave_red_sum(hx * jw.x + hy * jw.y);
  __shared__ float red[4];
  int lane = threadIdx.x & 63, wv = threadIdx.x >> 6;
  if (lane == 0) red[wv] = p;
  __syncthreads();
  if (threadIdx.x == 0){
    float tot = red[0] + red[1] + red[2] + red[3];
    if (accum) score[n] += tot; else score[n] = tot;
  }
}

// ---------------- JK softmax combine (xs in bf16) ----------------
__global__ __launch_bounds__(256) void k_jk(const float* __restrict__ scores,
                                            const __hip_bfloat16* __restrict__ xsb,
                                            float* __restrict__ out)
{
  int n = blockIdx.x, cx = threadIdx.x;
  float s0 = scores[n], s1 = scores[N_NODES + n];
  float s2 = scores[2 * N_NODES + n], s3 = scores[3 * N_NODES + n];
  float mx = fmaxf(fmaxf(s0, s1), fmaxf(s2, s3));
  float e0 = expf(s0 - mx), e1 = expf(s1 - mx), e2 = expf(s2 - mx), e3 = expf(s3 - mx);
  float inv = 1.f / (e0 + e1 + e2 + e3);
  size_t idx = (size_t)n * CH + cx;
  const size_t NC = (size_t)N_NODES * CH;
  float v = e0 * __bfloat162float(xsb[idx]) + e1 * __bfloat162float(xsb[NC + idx]) +
            e2 * __bfloat162float(xsb[2 * NC + idx]) + e3 * __bfloat162float(xsb[3 * NC + idx]);
  out[idx] = v * inv;
}

// ---------------- batch-norm style final ----------------
__global__ __launch_bounds__(256) void k_bnred(const float* __restrict__ out,
                                               float* __restrict__ sums)
{
  int cx = threadIdx.x;
  float s = 0.f, s2 = 0.f;
  for (int n = blockIdx.x; n < N_NODES; n += gridDim.x){
    float v = out[(size_t)n * CH + cx];
    s += v;
    s2 = fmaf(v, v, s2);
  }
  atomicAdd(&sums[cx], s);
  atomicAdd(&sums[CH + cx], s2);
}

__global__ __launch_bounds__(256) void k_bnapply(float* __restrict__ out,
                                                 const float* __restrict__ sums,
                                                 const float* __restrict__ gamma,
                                                 const float* __restrict__ beta)
{
  int idx = blockIdx.x * 256 + threadIdx.x;
  int cx = idx & 255;
  const float invN = 1.f / (float)N_NODES;
  float mean = sums[cx] * invN;
  float var = sums[CH + cx] * invN - mean * mean;
  out[idx] = (out[idx] - mean) * rsqrtf(var + EPS) * gamma[cx] + beta[cx];
}

// ---------------- host ----------------
extern "C" void kernel_launch(void* const* d_in, const int* in_sizes, int n_in,
                              void* d_out, int out_size, void* d_ws, size_t ws_size,
                              hipStream_t stream)
{
  const float* x     = (const float*)d_in[0];
  const int*   eidx  = (const int*)d_in[1];
  const int*   srcp  = eidx;
  const int*   dstp  = eidx + N_EDGES;
  const float* ea    = (const float*)d_in[2];
  const float* Wl0   = (const float*)d_in[3];
  const float* Wr0   = (const float*)d_in[4];
  const float* We0   = (const float*)d_in[5];
  const float* att0  = (const float*)d_in[6];
  const float* b0    = (const float*)d_in[7];
  const float* WlR   = (const float*)d_in[8];
  const float* WrR   = (const float*)d_in[9];
  const float* WeR   = (const float*)d_in[10];
  const float* attR  = (const float*)d_in[11];
  const float* bR    = (const float*)d_in[12];
  const float* Wih_f = (const float*)d_in[13];
  const float* Whh_f = (const float*)d_in[14];
  const float* bih_f = (const float*)d_in[15];
  const float* bhh_f = (const float*)d_in[16];
  const float* Wih_b = (const float*)d_in[17];
  const float* Whh_b = (const float*)d_in[18];
  const float* bih_b = (const float*)d_in[19];
  const float* bhh_b = (const float*)d_in[20];
  const float* jkw   = (const float*)d_in[21];
  const float* gamma = (const float*)d_in[23];
  const float* beta  = (const float*)d_in[24];

  // ---------- byte-precise workspace layout ----------
  char* base = (char*)d_ws;
  const size_t NC   = (size_t)N_NODES * CH;          // 5,120,000 elems
  const size_t NH   = (size_t)N_NODES * HID;         // 10,240,000 elems
  size_t off = 0;
  __hip_bfloat16* wihf_b = (__hip_bfloat16*)(base + off); off += (size_t)G4 * CH * 2;
  __hip_bfloat16* whhf_b = (__hip_bfloat16*)(base + off); off += (size_t)G4 * HID * 2;
  __hip_bfloat16* wihb_b = (__hip_bfloat16*)(base + off); off += (size_t)G4 * CH * 2;
  __hip_bfloat16* whhb_b = (__hip_bfloat16*)(base + off); off += (size_t)G4 * HID * 2;
  float* scores = (float*)(base + off); off += (size_t)LAYERS * N_NODES * 4;
  float* sums   = (float*)(base + off); off += 2048;
  __hip_bfloat16* xsb = (__hip_bfloat16*)(base + off); off += LAYERS * NC * 2;
  const size_t R = off;                              // shared region base (~47.6 MB)
  // GAT view of R
  float* xin0  = (float*)(base + R);                 // ping [N][CH] f32
  float* xin1  = xin0 + NC;                          // pong
  float* xl    = xin1 + NC;
  float* xr    = xl + NC;
  int*   indptr = (int*)(xr + NC);                   // N+1
  int*   cursor = indptr + (N_NODES + 1);            // N
  int*   esrc   = cursor + N_NODES;                  // E (dst-sorted src)
  float* eea    = (float*)(esrc + N_EDGES);          // E (dst-sorted edge_attr)
  const size_t gat_end = R + 4 * NC * 4
                       + (2 * (size_t)N_NODES + 1 + 2 * (size_t)N_EDGES) * 4;
  // LSTM view of R
  __hip_bfloat16* hbuf = (__hip_bfloat16*)(base + R); // [N][HID] bf16
  float* cbuf  = (float*)(base + R + NH * 2);         // [N][HID] f32
  __hip_bfloat16* gates = (__hip_bfloat16*)(base + R + NH * 2 + NH * 4);
  const size_t lstm_fixed = R + NH * 2 + NH * 4;

  if (gat_end > ws_size) return;                     // leave output poisoned
  long long gc_ll = ((long long)ws_size - (long long)lstm_fixed) / ((long long)G4 * 2);
  if (gc_ll > N_NODES) gc_ll = N_NODES;
  if (gc_ll < 128) return;
  const int GC = (int)(gc_ll & ~127LL);              // multiple of 128 tiles

  // ---- CSR by dst (src/ea stored dst-sorted) ----
  hipMemsetAsync(cursor, 0, N_NODES * sizeof(int), stream);
  k_hist<<<(N_EDGES + 255) / 256, 256, 0, stream>>>(dstp, cursor);
  k_scan<<<1, 1024, 0, stream>>>(cursor, indptr, cursor);
  k_scatter<<<(N_EDGES + 255) / 256, 256, 0, stream>>>(srcp, dstp, ea, cursor,
                                                       esrc, eea);

  // ---- LSTM weight converts ----
  k_f2b<<<((int)((size_t)G4 * CH) + 255) / 256, 256, 0, stream>>>(Wih_f, wihf_b, G4 * CH);
  k_f2b<<<((int)((size_t)G4 * HID) + 255) / 256, 256, 0, stream>>>(Whh_f, whhf_b, G4 * HID);
  k_f2b<<<((int)((size_t)G4 * CH) + 255) / 256, 256, 0, stream>>>(Wih_b, wihb_b, G4 * CH);
  k_f2b<<<((int)((size_t)G4 * HID) + 255) / 256, 256, 0, stream>>>(Whh_b, whhb_b, G4 * HID);

  // ---- GATv2 layers (f32 chain; xs stored bf16) ----
  float* ping = xin0; float* pong = xin1;
  for (int l = 0; l < LAYERS; ++l){
    if (l == 0){
      k_xf0<<<(int)(NC / 256), 256, 0, stream>>>(x, Wl0, Wr0, xl, xr);
    } else {
      k_gemm<<<dim3(157, 2), 256, 0, stream>>>(
          ping, WlR + (size_t)(l - 1) * CH * CH, CH, xl, N_NODES, CH);
      k_gemm<<<dim3(157, 2), 256, 0, stream>>>(
          ping, WrR + (size_t)(l - 1) * CH * CH, CH, xr, N_NODES, CH);
    }
    const float* We  = (l == 0) ? We0  : WeR  + (size_t)(l - 1) * CH;
    const float* att = (l == 0) ? att0 : attR + (size_t)(l - 1) * CH;
    const float* bia = (l == 0) ? b0   : bR   + (size_t)(l - 1) * CH;
    k_gat<<<N_NODES, 256, 0, stream>>>(indptr, esrc, eea, xl, xr, We, att, bia,
                                       pong, xsb + (size_t)l * NC);
    float* tmp = ping; ping = pong; pong = tmp;
  }

  // ---- LSTM forward (t=0: h,c are zero -> skip Whh phase, first flag) ----
  for (int t = 0; t < LAYERS; t++){
    for (int c0 = 0; c0 < N_NODES; c0 += GC){
      int mm = (N_NODES - c0 < GC) ? (N_NODES - c0) : GC;
      k_gemm_bf<<<dim3((mm + 127) / 128, G4 / 128), 256, 0, stream>>>(
          xsb + (size_t)t * NC + (size_t)c0 * CH, CH,
          hbuf + (size_t)c0 * HID, (t == 0) ? 0 : HID,
          wihf_b, whhf_b, bih_f, bhh_f, gates, mm, G4);
      k_cell<<<mm, 256, 0, stream>>>(gates, hbuf + (size_t)c0 * HID,
                                     cbuf + (size_t)c0 * HID, jkw,
                                     scores + (size_t)t * N_NODES + c0, 0, t == 0);
    }
  }
  // ---- LSTM backward ----
  for (int s = 0; s < LAYERS; s++){
    int t = LAYERS - 1 - s;
    for (int c0 = 0; c0 < N_NODES; c0 += GC){
      int mm = (N_NODES - c0 < GC) ? (N_NODES - c0) : GC;
      k_gemm_bf<<<dim3((mm + 127) / 128, G4 / 128), 256, 0, stream>>>(
          xsb + (size_t)t * NC + (size_t)c0 * CH, CH,
          hbuf + (size_t)c0 * HID, (s == 0) ? 0 : HID,
          wihb_b, whhb_b, bih_b, bhh_b, gates, mm, G4);
      k_cell<<<mm, 256, 0, stream>>>(gates, hbuf + (size_t)c0 * HID,
                                     cbuf + (size_t)c0 * HID, jkw + HID,
                                     scores + (size_t)t * N_NODES + c0, 1, s == 0);
    }
  }

  // ---- JK combine + final norm ----
  k_jk<<<N_NODES, 256, 0, stream>>>(scores, xsb, (float*)d_out);
  hipMemsetAsync(sums, 0, 2048, stream);
  k_bnred<<<256, 256, 0, stream>>>((const float*)d_out, sums);
  k_bnapply<<<(int)(NC / 256), 256, 0, stream>>>((float*)d_out, sums, gamma, beta);
}

// Round 8
// 1996.014 us; speedup vs baseline: 8.5642x; 1.2539x over previous
//
#include <hip/hip_runtime.h>
#include <hip/hip_bf16.h>
#include <math.h>

#define N_NODES 20000
#define N_EDGES 640000
#define CH 256        // HEADS*DIM
#define LAYERS 4
#define HID 512
#define G4 2048       // 4*HID
#define EPS 1e-5f
#define SLOPE 0.2f

typedef __bf16 bf16x8 __attribute__((ext_vector_type(8)));
typedef float  f32x4  __attribute__((ext_vector_type(4)));

// ---------------- helpers ----------------
__device__ __forceinline__ float wave_red_sum(float v){
#pragma unroll
  for (int off = 32; off; off >>= 1) v += __shfl_xor(v, off, 64);
  return v;
}

// async global->LDS, 16B per lane; lds dest = wave-uniform base + lane*16
__device__ __forceinline__ void gload16(const void* g, void* l){
  __builtin_amdgcn_global_load_lds(
      (const __attribute__((address_space(1))) void*)g,
      (__attribute__((address_space(3))) void*)l, 16, 0, 0);
}

// bf16 pair -> float2 (bf16->f32 is a 16-bit shift)
__device__ __forceinline__ float2 ldbf2(const __hip_bfloat16* p){
  unsigned u = *(const unsigned*)p;
  float2 r;
  r.x = __uint_as_float(u << 16);
  r.y = __uint_as_float(u & 0xffff0000u);
  return r;
}

// ---------------- CSR build ----------------
__global__ void k_hist(const int* __restrict__ dst, int* __restrict__ cnt){
  int e = blockIdx.x * 256 + threadIdx.x;
  if (e < N_EDGES) atomicAdd(&cnt[dst[e]], 1);
}

__global__ __launch_bounds__(1024) void k_scan(const int* __restrict__ cnt,
                                               int* __restrict__ indptr,
                                               int* __restrict__ cursor){
  __shared__ int buf[1024];
  __shared__ int carry;
  if (threadIdx.x == 0) carry = 0;
  __syncthreads();
  for (int base = 0; base < N_NODES; base += 1024){
    int i = base + threadIdx.x;
    int v = (i < N_NODES) ? cnt[i] : 0;
    buf[threadIdx.x] = v;
    __syncthreads();
#pragma unroll
    for (int off = 1; off < 1024; off <<= 1){
      int t = (threadIdx.x >= off) ? buf[threadIdx.x - off] : 0;
      __syncthreads();
      buf[threadIdx.x] += t;
      __syncthreads();
    }
    int excl = buf[threadIdx.x] - v;
    if (i < N_NODES){
      indptr[i] = carry + excl;
      cursor[i] = carry + excl;
    }
    __syncthreads();
    if (threadIdx.x == 0) carry += buf[1023];
    __syncthreads();
  }
  if (threadIdx.x == 0) indptr[N_NODES] = carry;
}

// scatter src + edge_attr into dst-sorted order
__global__ void k_scatter(const int* __restrict__ src, const int* __restrict__ dst,
                          const float* __restrict__ ea, int* __restrict__ cursor,
                          int* __restrict__ esrc, float* __restrict__ eea){
  int e = blockIdx.x * 256 + threadIdx.x;
  if (e < N_EDGES){
    int pos = atomicAdd(&cursor[dst[e]], 1);
    esrc[pos] = src[e];
    eea[pos] = ea[e];
  }
}

// ---------------- LSTM weight permute+convert ----------------
// in row r = g*512 + j  ->  out row nr = (j/16)*64 + g*16 + (j%16)
__global__ void k_wperm(const float* __restrict__ W, __hip_bfloat16* __restrict__ Wp,
                        int K){
  int idx = blockIdx.x * 256 + threadIdx.x;
  if (idx >= G4 * K) return;
  int r = idx / K, k = idx - r * K;
  int g = r >> 9, j = r & 511;
  int nr = ((j >> 4) << 6) + (g << 4) + (j & 15);
  Wp[(size_t)nr * K + k] = __float2bfloat16(W[idx]);
}

__global__ void k_bperm(const float* __restrict__ bih, const float* __restrict__ bhh,
                        float* __restrict__ bp){
  int r = blockIdx.x * 256 + threadIdx.x;   // 0..2047
  if (r >= G4) return;
  int g = r >> 9, j = r & 511;
  int nr = ((j >> 4) << 6) + (g << 4) + (j & 15);
  bp[nr] = bih[r] + bhh[r];
}

// ---------------- layer-0 transform (K=2): xl -> bf16 only, xr -> f32 ----------------
__global__ void k_xf0(const float* __restrict__ x, const float* __restrict__ Wl,
                      const float* __restrict__ Wr, __hip_bfloat16* __restrict__ xlb,
                      float* __restrict__ xr){
  int idx = blockIdx.x * 256 + threadIdx.x;
  int n = idx >> 8, cx = idx & 255;
  float x0 = x[n * 2], x1 = x[n * 2 + 1];
  xlb[idx] = __float2bfloat16(fmaf(x0, Wl[cx], x1 * Wl[CH + cx]));
  xr[idx]  = fmaf(x0, Wr[cx], x1 * Wr[CH + cx]);
}

// ---------------- f32 GEMM (GAT transforms): C = A*B, B k-major [K][Nc] ----------------
// writes f32 (Cc) and/or bf16 (Cb) — either may be null
__global__ __launch_bounds__(256) void k_gemm(
    const float* __restrict__ A, const float* __restrict__ B, int K,
    float* __restrict__ Cc, __hip_bfloat16* __restrict__ Cb, int M, int Nc)
{
  __shared__ float As[16][132];
  __shared__ float Bs[16][132];
  const int tid = threadIdx.x;
  const int tx = tid & 15, ty = tid >> 4;
  const int m0 = blockIdx.x * 128, n0 = blockIdx.y * 128;
  float acc[2][2][4][4];
#pragma unroll
  for (int a = 0; a < 2; a++)
#pragma unroll
    for (int b = 0; b < 2; b++)
#pragma unroll
      for (int i = 0; i < 4; i++)
#pragma unroll
        for (int j = 0; j < 4; j++) acc[a][b][i][j] = 0.f;

  for (int k0 = 0; k0 < K; k0 += 16){
#pragma unroll
    for (int i = 0; i < 8; i++){
      int id = tid + i * 256;
      int kk = id & 15, r = id >> 4;
      int m = m0 + r;
      As[kk][r] = (m < M) ? A[(size_t)m * K + (k0 + kk)] : 0.f;
    }
#pragma unroll
    for (int i = 0; i < 8; i++){
      int id = tid + i * 256;
      int j = id & 127, kk = id >> 7;
      Bs[kk][j] = B[(size_t)(k0 + kk) * Nc + (n0 + j)];
    }
    __syncthreads();
#pragma unroll
    for (int kk = 0; kk < 16; kk++){
      float4 a0 = *(const float4*)&As[kk][ty * 4];
      float4 a1 = *(const float4*)&As[kk][ty * 4 + 64];
      float4 b0 = *(const float4*)&Bs[kk][tx * 4];
      float4 b1 = *(const float4*)&Bs[kk][tx * 4 + 64];
      float av[2][4] = {{a0.x, a0.y, a0.z, a0.w}, {a1.x, a1.y, a1.z, a1.w}};
      float bv[2][4] = {{b0.x, b0.y, b0.z, b0.w}, {b1.x, b1.y, b1.z, b1.w}};
#pragma unroll
      for (int bi = 0; bi < 2; bi++)
#pragma unroll
        for (int i = 0; i < 4; i++)
#pragma unroll
          for (int bj = 0; bj < 2; bj++)
#pragma unroll
            for (int j = 0; j < 4; j++)
              acc[bi][bj][i][j] = fmaf(av[bi][i], bv[bj][j], acc[bi][bj][i][j]);
    }
    __syncthreads();
  }
#pragma unroll
  for (int bj = 0; bj < 2; bj++){
    int c0 = n0 + bj * 64 + tx * 4;
#pragma unroll
    for (int bi = 0; bi < 2; bi++)
#pragma unroll
      for (int i = 0; i < 4; i++){
        int m = m0 + bi * 64 + ty * 4 + i;
        if (m < M){
          if (Cc){
            float4 v = make_float4(acc[bi][bj][i][0], acc[bi][bj][i][1],
                                   acc[bi][bj][i][2], acc[bi][bj][i][3]);
            *(float4*)&Cc[(size_t)m * Nc + c0] = v;
          }
          if (Cb){
            ushort4 b;
            b.x = __bfloat16_as_ushort(__float2bfloat16(acc[bi][bj][i][0]));
            b.y = __bfloat16_as_ushort(__float2bfloat16(acc[bi][bj][i][1]));
            b.z = __bfloat16_as_ushort(__float2bfloat16(acc[bi][bj][i][2]));
            b.w = __bfloat16_as_ushort(__float2bfloat16(acc[bi][bj][i][3]));
            *(ushort4*)&Cb[(size_t)m * Nc + c0] = b;
          }
        }
      }
  }
}

// ---------------- fused LSTM step: gates GEMM + cell + JK partial ----------------
// A1:[M][256] bf16 (xs_t), A2:[M][512] bf16 (h_in, K2=0 at t=0)
// B1/B2: PERMUTED weights [2048][K] bf16; biasp: permuted bih+bhh [2048] f32
// col layout: col = block64*64 + gate*16 + (j%16), block64 = j/16 -> wave quadrant
// fj = gate, same lane holds all 4 gates of hidden j. Epilogue does the cell.
// h_out MUST be a different buffer than h_in (A2 is read by all y-blocks of the
// same m0 while the epilogue writes h rows m0..m0+127 -> double-buffered).
__global__ __launch_bounds__(256) void k_lstm_step(
    const __hip_bfloat16* __restrict__ A1, int K1,
    const __hip_bfloat16* __restrict__ A2, int K2,
    const __hip_bfloat16* __restrict__ B1, const __hip_bfloat16* __restrict__ B2,
    const float* __restrict__ biasp, __hip_bfloat16* __restrict__ h_out,
    float* __restrict__ c, const float* __restrict__ jkw,
    float* __restrict__ score, int M, int first)
{
  __shared__ __align__(16) unsigned short As[128 * 32];
  __shared__ __align__(16) unsigned short Bs[128 * 32];
  const int tid = threadIdx.x;
  const int lane = tid & 63, w = tid >> 6;
  const int wr = w >> 1, wc = w & 1;
  const int m0 = blockIdx.x * 128, n0 = blockIdx.y * 128;
  const int l15 = lane & 15, l4 = lane >> 4;
  const int srow = lane >> 2;
  const int skk  = (lane & 3) * 8;

  f32x4 acc[4][4];
#pragma unroll
  for (int i = 0; i < 4; i++)
#pragma unroll
    for (int j = 0; j < 4; j++) acc[i][j] = (f32x4){0.f, 0.f, 0.f, 0.f};

  const int nt1 = K1 / 32, nt2 = K2 / 32;

  for (int kt = 0; kt < nt1 + nt2; ++kt){
    const __hip_bfloat16* Ab; const __hip_bfloat16* Bb; int K, k0;
    if (kt < nt1){ Ab = A1; Bb = B1; K = K1; k0 = kt * 32; }
    else         { Ab = A2; Bb = B2; K = K2; k0 = (kt - nt1) * 32; }
#pragma unroll
    for (int i = 0; i < 2; i++){
      int rbase = w * 32 + i * 16;
      int row = rbase + srow;
      gload16(Ab + (size_t)(m0 + row) * K + k0 + skk, &As[rbase * 32]);
      gload16(Bb + (size_t)(n0 + row) * K + k0 + skk, &Bs[rbase * 32]);
    }
    __syncthreads();
    bf16x8 af[4], bfr[4];
#pragma unroll
    for (int f = 0; f < 4; f++){
      af[f]  = *(const bf16x8*)&As[(wr * 64 + f * 16 + l15) * 32 + l4 * 8];
      bfr[f] = *(const bf16x8*)&Bs[(wc * 64 + f * 16 + l15) * 32 + l4 * 8];
    }
#pragma unroll
    for (int fi = 0; fi < 4; fi++)
#pragma unroll
      for (int fj = 0; fj < 4; fj++)
        acc[fi][fj] = __builtin_amdgcn_mfma_f32_16x16x32_bf16(af[fi], bfr[fj],
                                                              acc[fi][fj], 0, 0, 0);
    __syncthreads();
  }

  // ---- fused cell epilogue ----
  const int block64 = blockIdx.y * 2 + wc;     // 0..31
  const int j = block64 * 16 + l15;            // hidden channel 0..511
  const float bi0 = biasp[block64 * 64 + l15];
  const float bi1 = biasp[block64 * 64 + 16 + l15];
  const float bi2 = biasp[block64 * 64 + 32 + l15];
  const float bi3 = biasp[block64 * 64 + 48 + l15];
  const float jw  = jkw[j];
#pragma unroll
  for (int fi = 0; fi < 4; fi++){
#pragma unroll
    for (int r = 0; r < 4; r++){
      int node = m0 + wr * 64 + fi * 16 + l4 * 4 + r;
      float p = 0.f;
      if (node < M){
        float gi = acc[fi][0][r] + bi0;
        float gf = acc[fi][1][r] + bi1;
        float gg = acc[fi][2][r] + bi2;
        float go = acc[fi][3][r] + bi3;
        size_t hb = (size_t)node * HID + j;
        float cv = first ? 0.f : c[hb];
        float iv = 1.f / (1.f + __expf(-gi));
        float fv = 1.f / (1.f + __expf(-gf));
        float ov = 1.f / (1.f + __expf(-go));
        float cn = fv * cv + iv * tanhf(gg);
        float hn = ov * tanhf(cn);
        c[hb] = cn;
        h_out[hb] = __float2bfloat16(hn);
        p = hn * jw;
      }
      p += __shfl_xor(p, 1, 64); p += __shfl_xor(p, 2, 64);
      p += __shfl_xor(p, 4, 64); p += __shfl_xor(p, 8, 64);
      if (l15 == 0 && node < M) atomicAdd(&score[node], p);
    }
  }
}

// ---------------- fused GAT message pass (bf16 gathers, 128 thr = ch pairs) ----------------
__global__ __launch_bounds__(128) void k_gat(
    const int* __restrict__ indptr, const int* __restrict__ esrc,
    const float* __restrict__ eea, const __hip_bfloat16* __restrict__ xlb,
    const float* __restrict__ xr, const float* __restrict__ We,
    const float* __restrict__ att, const float* __restrict__ bias,
    float* __restrict__ xnext, __hip_bfloat16* __restrict__ xsb)
{
  const int n = blockIdx.x;
  const int t = threadIdx.x;              // ch pair (2t, 2t+1); head = t>>5
  const int c0 = 2 * t;
  const int s0 = indptr[n], s1 = indptr[n + 1];
  const float2 xr_t = *(const float2*)&xr[(size_t)n * CH + c0];
  const float2 We_t = *(const float2*)&We[c0];
  const float2 at_t = *(const float2*)&att[c0];
  float m = -1e30f, l = 0.f;
  float2 acc = make_float2(0.f, 0.f);

  int i = s0;
  for (; i + 1 < s1; i += 2){             // 2-way unroll: both gathers in flight
    int   sA = esrc[i],  sB = esrc[i + 1];
    float aA = eea[i],   aB = eea[i + 1];
    float2 xvA = ldbf2(xlb + (size_t)sA * CH + c0);
    float2 xvB = ldbf2(xlb + (size_t)sB * CH + c0);
    float vx = xvA.x + xr_t.x + aA * We_t.x;
    float vy = xvA.y + xr_t.y + aA * We_t.y;
    vx = vx > 0.f ? vx : SLOPE * vx;
    vy = vy > 0.f ? vy : SLOPE * vy;
    float pl = vx * at_t.x + vy * at_t.y;
    pl += __shfl_xor(pl, 16, 64); pl += __shfl_xor(pl, 8, 64);
    pl += __shfl_xor(pl, 4, 64);  pl += __shfl_xor(pl, 2, 64);
    pl += __shfl_xor(pl, 1, 64);                       // lgA (per 32-lane head)
    float wx = xvB.x + xr_t.x + aB * We_t.x;
    float wy = xvB.y + xr_t.y + aB * We_t.y;
    wx = wx > 0.f ? wx : SLOPE * wx;
    wy = wy > 0.f ? wy : SLOPE * wy;
    float pm = wx * at_t.x + wy * at_t.y;
    pm += __shfl_xor(pm, 16, 64); pm += __shfl_xor(pm, 8, 64);
    pm += __shfl_xor(pm, 4, 64);  pm += __shfl_xor(pm, 2, 64);
    pm += __shfl_xor(pm, 1, 64);                       // lgB
    float mn = fmaxf(m, pl);
    float sc = __expf(m - mn), wA = __expf(pl - mn);
    l = l * sc + wA;
    acc.x = acc.x * sc + wA * xvA.x;
    acc.y = acc.y * sc + wA * xvA.y;
    m = mn;
    mn = fmaxf(m, pm);
    sc = __expf(m - mn); float wB = __expf(pm - mn);
    l = l * sc + wB;
    acc.x = acc.x * sc + wB * xvB.x;
    acc.y = acc.y * sc + wB * xvB.y;
    m = mn;
  }
  if (i < s1){
    int   sA = esrc[i];
    float aA = eea[i];
    float2 xvA = ldbf2(xlb + (size_t)sA * CH + c0);
    float vx = xvA.x + xr_t.x + aA * We_t.x;
    float vy = xvA.y + xr_t.y + aA * We_t.y;
    vx = vx > 0.f ? vx : SLOPE * vx;
    vy = vy > 0.f ? vy : SLOPE * vy;
    float pl = vx * at_t.x + vy * at_t.y;
    pl += __shfl_xor(pl, 16, 64); pl += __shfl_xor(pl, 8, 64);
    pl += __shfl_xor(pl, 4, 64);  pl += __shfl_xor(pl, 2, 64);
    pl += __shfl_xor(pl, 1, 64);
    float mn = fmaxf(m, pl);
    float sc = __expf(m - mn), wA = __expf(pl - mn);
    l = l * sc + wA;
    acc.x = acc.x * sc + wA * xvA.x;
    acc.y = acc.y * sc + wA * xvA.y;
    m = mn;
  }
  float invl = (l > 0.f) ? 1.f / l : 0.f;
  float2 bia = *(const float2*)&bias[c0];
  float ox = acc.x * invl + bia.x;
  float oy = acc.y * invl + bia.y;
  ox = ox > 0.f ? ox : 0.f;
  oy = oy > 0.f ? oy : 0.f;
  size_t idx = (size_t)n * CH + c0;
  *(float2*)&xnext[idx] = make_float2(ox, oy);
  ushort2 hp;
  hp.x = __bfloat16_as_ushort(__float2bfloat16(ox));
  hp.y = __bfloat16_as_ushort(__float2bfloat16(oy));
  *(ushort2*)&xsb[idx] = hp;
}

// ---------------- JK softmax combine + BN reduction (fused) ----------------
__global__ __launch_bounds__(256) void k_jk(const float* __restrict__ scores,
                                            const __hip_bfloat16* __restrict__ xsb,
                                            float* __restrict__ out,
                                            float* __restrict__ sums)
{
  const int cx = threadIdx.x;
  const size_t NC = (size_t)N_NODES * CH;
  float s = 0.f, s2 = 0.f;
  for (int n = blockIdx.x; n < N_NODES; n += gridDim.x){
    float s0 = scores[n], s1 = scores[N_NODES + n];
    float sc2 = scores[2 * N_NODES + n], s3 = scores[3 * N_NODES + n];
    float mx = fmaxf(fmaxf(s0, s1), fmaxf(sc2, s3));
    float e0 = __expf(s0 - mx), e1 = __expf(s1 - mx);
    float e2 = __expf(sc2 - mx), e3 = __expf(s3 - mx);
    float inv = 1.f / (e0 + e1 + e2 + e3);
    size_t idx = (size_t)n * CH + cx;
    float v = e0 * __bfloat162float(xsb[idx]) + e1 * __bfloat162float(xsb[NC + idx]) +
              e2 * __bfloat162float(xsb[2 * NC + idx]) +
              e3 * __bfloat162float(xsb[3 * NC + idx]);
    v *= inv;
    out[idx] = v;
    s += v;
    s2 = fmaf(v, v, s2);
  }
  atomicAdd(&sums[cx], s);
  atomicAdd(&sums[CH + cx], s2);
}

__global__ __launch_bounds__(256) void k_bnapply(float* __restrict__ out,
                                                 const float* __restrict__ sums,
                                                 const float* __restrict__ gamma,
                                                 const float* __restrict__ beta)
{
  int idx = blockIdx.x * 256 + threadIdx.x;
  int cx = idx & 255;
  const float invN = 1.f / (float)N_NODES;
  float mean = sums[cx] * invN;
  float var = sums[CH + cx] * invN - mean * mean;
  out[idx] = (out[idx] - mean) * rsqrtf(var + EPS) * gamma[cx] + beta[cx];
}

// ---------------- host ----------------
extern "C" void kernel_launch(void* const* d_in, const int* in_sizes, int n_in,
                              void* d_out, int out_size, void* d_ws, size_t ws_size,
                              hipStream_t stream)
{
  const float* x     = (const float*)d_in[0];
  const int*   eidx  = (const int*)d_in[1];
  const int*   srcp  = eidx;
  const int*   dstp  = eidx + N_EDGES;
  const float* ea    = (const float*)d_in[2];
  const float* Wl0   = (const float*)d_in[3];
  const float* Wr0   = (const float*)d_in[4];
  const float* We0   = (const float*)d_in[5];
  const float* att0  = (const float*)d_in[6];
  const float* b0    = (const float*)d_in[7];
  const float* WlR   = (const float*)d_in[8];
  const float* WrR   = (const float*)d_in[9];
  const float* WeR   = (const float*)d_in[10];
  const float* attR  = (const float*)d_in[11];
  const float* bR    = (const float*)d_in[12];
  const float* Wih_f = (const float*)d_in[13];
  const float* Whh_f = (const float*)d_in[14];
  const float* bih_f = (const float*)d_in[15];
  const float* bhh_f = (const float*)d_in[16];
  const float* Wih_b = (const float*)d_in[17];
  const float* Whh_b = (const float*)d_in[18];
  const float* bih_b = (const float*)d_in[19];
  const float* bhh_b = (const float*)d_in[20];
  const float* jkw   = (const float*)d_in[21];
  const float* gamma = (const float*)d_in[23];
  const float* beta  = (const float*)d_in[24];

  // ---------- byte-precise workspace layout ----------
  char* base = (char*)d_ws;
  const size_t NC   = (size_t)N_NODES * CH;          // 5,120,000 elems
  const size_t NH   = (size_t)N_NODES * HID;         // 10,240,000 elems
  size_t off = 0;
  __hip_bfloat16* wihf_p = (__hip_bfloat16*)(base + off); off += (size_t)G4 * CH * 2;
  __hip_bfloat16* whhf_p = (__hip_bfloat16*)(base + off); off += (size_t)G4 * HID * 2;
  __hip_bfloat16* wihb_p = (__hip_bfloat16*)(base + off); off += (size_t)G4 * CH * 2;
  __hip_bfloat16* whhb_p = (__hip_bfloat16*)(base + off); off += (size_t)G4 * HID * 2;
  float* biasf_p = (float*)(base + off); off += G4 * 4;
  float* biasb_p = (float*)(base + off); off += G4 * 4;
  float* scores  = (float*)(base + off); off += (size_t)LAYERS * N_NODES * 4;
  float* sums    = (float*)(base + off); off += 2048;
  __hip_bfloat16* xsb = (__hip_bfloat16*)(base + off); off += LAYERS * NC * 2;
  const size_t R = off;                              // shared region base (~47.6 MB)
  // GAT view of R
  float* xin0  = (float*)(base + R);                 // ping [N][CH] f32
  float* xin1  = xin0 + NC;                          // pong
  float* xr    = xin1 + NC;                          // f32 target transform
  __hip_bfloat16* xlb = (__hip_bfloat16*)(xr + NC);  // bf16 source transform
  int*   indptr = (int*)(xlb + NC);                  // N+1
  int*   cursor = indptr + (N_NODES + 1);            // N
  int*   esrc   = cursor + N_NODES;                  // E (dst-sorted src)
  float* eea    = (float*)(esrc + N_EDGES);          // E (dst-sorted edge_attr)
  const size_t gat_end = R + 3 * NC * 4 + NC * 2
                       + (2 * (size_t)N_NODES + 1 + 2 * (size_t)N_EDGES) * 4;
  // LSTM view of R (h double-buffered to kill the A2-read vs h-write race)
  __hip_bfloat16* hbuf0 = (__hip_bfloat16*)(base + R);            // [N][HID] bf16
  float* cbuf  = (float*)(base + R + NH * 2);                     // [N][HID] f32
  __hip_bfloat16* hbuf1 = (__hip_bfloat16*)(base + R + NH * 2 + NH * 4);
  const size_t lstm_end = R + NH * 2 + NH * 4 + NH * 2;

  if (gat_end > ws_size || lstm_end > ws_size) return;  // leave output poisoned

  // ---- CSR by dst (src/ea stored dst-sorted) ----
  hipMemsetAsync(cursor, 0, N_NODES * sizeof(int), stream);
  k_hist<<<(N_EDGES + 255) / 256, 256, 0, stream>>>(dstp, cursor);
  k_scan<<<1, 1024, 0, stream>>>(cursor, indptr, cursor);
  k_scatter<<<(N_EDGES + 255) / 256, 256, 0, stream>>>(srcp, dstp, ea, cursor,
                                                       esrc, eea);

  // ---- LSTM weight permute+convert ----
  k_wperm<<<(G4 * CH + 255) / 256, 256, 0, stream>>>(Wih_f, wihf_p, CH);
  k_wperm<<<(G4 * HID + 255) / 256, 256, 0, stream>>>(Whh_f, whhf_p, HID);
  k_wperm<<<(G4 * CH + 255) / 256, 256, 0, stream>>>(Wih_b, wihb_p, CH);
  k_wperm<<<(G4 * HID + 255) / 256, 256, 0, stream>>>(Whh_b, whhb_p, HID);
  k_bperm<<<(G4 + 255) / 256, 256, 0, stream>>>(bih_f, bhh_f, biasf_p);
  k_bperm<<<(G4 + 255) / 256, 256, 0, stream>>>(bih_b, bhh_b, biasb_p);

  // ---- GATv2 layers (f32 transform chain; xl gathered as bf16) ----
  float* ping = xin0; float* pong = xin1;
  for (int l = 0; l < LAYERS; ++l){
    if (l == 0){
      k_xf0<<<(int)(NC / 256), 256, 0, stream>>>(x, Wl0, Wr0, xlb, xr);
    } else {
      k_gemm<<<dim3(157, 2), 256, 0, stream>>>(
          ping, WlR + (size_t)(l - 1) * CH * CH, CH, nullptr, xlb, N_NODES, CH);
      k_gemm<<<dim3(157, 2), 256, 0, stream>>>(
          ping, WrR + (size_t)(l - 1) * CH * CH, CH, xr, nullptr, N_NODES, CH);
    }
    const float* We  = (l == 0) ? We0  : WeR  + (size_t)(l - 1) * CH;
    const float* att = (l == 0) ? att0 : attR + (size_t)(l - 1) * CH;
    const float* bia = (l == 0) ? b0   : bR   + (size_t)(l - 1) * CH;
    k_gat<<<N_NODES, 128, 0, stream>>>(indptr, esrc, eea, xlb, xr, We, att, bia,
                                       pong, xsb + (size_t)l * NC);
    float* tmp = ping; ping = pong; pong = tmp;
  }

  // ---- LSTM (scores accumulated atomically; zero once) ----
  __hip_bfloat16* hb[2] = {hbuf0, hbuf1};
  hipMemsetAsync(scores, 0, (size_t)LAYERS * N_NODES * 4, stream);
  for (int t = 0; t < LAYERS; t++){
    k_lstm_step<<<dim3(157, G4 / 128), 256, 0, stream>>>(
        xsb + (size_t)t * NC, CH, hb[(t + 1) & 1], (t == 0) ? 0 : HID,
        wihf_p, whhf_p, biasf_p, hb[t & 1], cbuf, jkw,
        scores + (size_t)t * N_NODES, N_NODES, t == 0);
  }
  for (int s = 0; s < LAYERS; s++){
    int t = LAYERS - 1 - s;
    k_lstm_step<<<dim3(157, G4 / 128), 256, 0, stream>>>(
        xsb + (size_t)t * NC, CH, hb[(s + 1) & 1], (s == 0) ? 0 : HID,
        wihb_p, whhb_p, biasb_p, hb[s & 1], cbuf, jkw + HID,
        scores + (size_t)t * N_NODES, N_NODES, s == 0);
  }

  // ---- JK combine (+BN reduce) + BN apply ----
  hipMemsetAsync(sums, 0, 2048, stream);
  k_jk<<<256, 256, 0, stream>>>(scores, xsb, (float*)d_out, sums);
  k_bnapply<<<(int)(NC / 256), 256, 0, stream>>>((float*)d_out, sums, gamma, beta);
}

// Round 10
// 1511.437 us; speedup vs baseline: 11.3100x; 1.3206x over previous
//
#include <hip/hip_runtime.h>
#include <hip/hip_bf16.h>
#include <math.h>

#define N_NODES 20000
#define N_EDGES 640000
#define CH 256        // HEADS*DIM
#define LAYERS 4
#define HID 512
#define G4 2048       // 4*HID
#define EPS 1e-5f
#define SLOPE 0.2f

typedef __bf16 bf16x8 __attribute__((ext_vector_type(8)));
typedef float  f32x4  __attribute__((ext_vector_type(4)));

// ---------------- helpers ----------------
// async global->LDS, 16B per lane; lds dest = wave-uniform base + lane*16
__device__ __forceinline__ void gload16(const void* g, void* l){
  __builtin_amdgcn_global_load_lds(
      (const __attribute__((address_space(1))) void*)g,
      (__attribute__((address_space(3))) void*)l, 16, 0, 0);
}

// bf16 pair -> float2 (bf16->f32 is a 16-bit shift)
__device__ __forceinline__ float2 ldbf2(const __hip_bfloat16* p){
  unsigned u = *(const unsigned*)p;
  float2 r;
  r.x = __uint_as_float(u << 16);
  r.y = __uint_as_float(u & 0xffff0000u);
  return r;
}

// bijective chunked XCD swizzle (m204): contiguous wgid ranges per XCD
__device__ __forceinline__ int xcd_swz(int orig, int q, int r){
  int xcd = orig & 7, idx = orig >> 3;
  return (xcd < r ? xcd * (q + 1) : r * (q + 1) + (xcd - r) * q) + idx;
}

// ---------------- CSR build ----------------
__global__ void k_hist(const int* __restrict__ dst, int* __restrict__ cnt){
  int e = blockIdx.x * 256 + threadIdx.x;
  if (e < N_EDGES) atomicAdd(&cnt[dst[e]], 1);
}

__global__ __launch_bounds__(1024) void k_scan(const int* __restrict__ cnt,
                                               int* __restrict__ indptr,
                                               int* __restrict__ cursor){
  __shared__ int buf[1024];
  __shared__ int carry;
  if (threadIdx.x == 0) carry = 0;
  __syncthreads();
  for (int base = 0; base < N_NODES; base += 1024){
    int i = base + threadIdx.x;
    int v = (i < N_NODES) ? cnt[i] : 0;
    buf[threadIdx.x] = v;
    __syncthreads();
#pragma unroll
    for (int off = 1; off < 1024; off <<= 1){
      int t = (threadIdx.x >= off) ? buf[threadIdx.x - off] : 0;
      __syncthreads();
      buf[threadIdx.x] += t;
      __syncthreads();
    }
    int excl = buf[threadIdx.x] - v;
    if (i < N_NODES){
      indptr[i] = carry + excl;
      cursor[i] = carry + excl;
    }
    __syncthreads();
    if (threadIdx.x == 0) carry += buf[1023];
    __syncthreads();
  }
  if (threadIdx.x == 0) indptr[N_NODES] = carry;
}

// scatter src + edge_attr into dst-sorted order
__global__ void k_scatter(const int* __restrict__ src, const int* __restrict__ dst,
                          const float* __restrict__ ea, int* __restrict__ cursor,
                          int* __restrict__ esrc, float* __restrict__ eea){
  int e = blockIdx.x * 256 + threadIdx.x;
  if (e < N_EDGES){
    int pos = atomicAdd(&cursor[dst[e]], 1);
    esrc[pos] = src[e];
    eea[pos] = ea[e];
  }
}

// ---------------- LSTM weight permute+convert ----------------
// in row r = g*512 + j  ->  out row nr = (j/16)*64 + g*16 + (j%16)
__global__ void k_wperm(const float* __restrict__ W, __hip_bfloat16* __restrict__ Wp,
                        int K){
  int idx = blockIdx.x * 256 + threadIdx.x;
  if (idx >= G4 * K) return;
  int r = idx / K, k = idx - r * K;
  int g = r >> 9, j = r & 511;
  int nr = ((j >> 4) << 6) + (g << 4) + (j & 15);
  Wp[(size_t)nr * K + k] = __float2bfloat16(W[idx]);
}

__global__ void k_bperm(const float* __restrict__ bih, const float* __restrict__ bhh,
                        float* __restrict__ bp){
  int r = blockIdx.x * 256 + threadIdx.x;   // 0..2047
  if (r >= G4) return;
  int g = r >> 9, j = r & 511;
  int nr = ((j >> 4) << 6) + (g << 4) + (j & 15);
  bp[nr] = bih[r] + bhh[r];
}

// GAT weight transpose+convert: Wl,Wr [K=256][N=256] k-major f32 ->
// out [512][256] n-major bf16 (rows 0-255 = Wl^T, 256-511 = Wr^T)
__global__ void k_wtrans(const float* __restrict__ Wl, const float* __restrict__ Wr,
                         __hip_bfloat16* __restrict__ out){
  int idx = blockIdx.x * 256 + threadIdx.x;
  if (idx >= CH * CH) return;
  int n = idx >> 8, k = idx & 255;
  out[(size_t)n * CH + k]        = __float2bfloat16(Wl[(size_t)k * CH + n]);
  out[(size_t)(CH + n) * CH + k] = __float2bfloat16(Wr[(size_t)k * CH + n]);
}

// ---------------- layer-0 transform (K=2): xl -> bf16, xr -> f32 ----------------
__global__ void k_xf0(const float* __restrict__ x, const float* __restrict__ Wl,
                      const float* __restrict__ Wr, __hip_bfloat16* __restrict__ xlb,
                      float* __restrict__ xr){
  int idx = blockIdx.x * 256 + threadIdx.x;
  int n = idx >> 8, cx = idx & 255;
  float x0 = x[n * 2], x1 = x[n * 2 + 1];
  xlb[idx] = __float2bfloat16(fmaf(x0, Wl[cx], x1 * Wl[CH + cx]));
  xr[idx]  = fmaf(x0, Wr[cx], x1 * Wr[CH + cx]);
}

// ---------------- fused GAT transform (MFMA): [xl|xr] = xs_prev * [Wl|Wr] ----------------
// A:[M][256] bf16, B:[512][256] bf16 n-major. cols 0-255 -> xlb bf16, 256-511 -> xr f32.
__global__ __launch_bounds__(256) void k_xform(
    const __hip_bfloat16* __restrict__ A, const __hip_bfloat16* __restrict__ B,
    __hip_bfloat16* __restrict__ xlb, float* __restrict__ xr, int M)
{
  __shared__ __align__(16) unsigned short As[128 * 32];
  __shared__ __align__(16) unsigned short Bs[128 * 32];
  const int wgid = xcd_swz(blockIdx.x, 628 >> 3, 628 & 7);
  const int m0 = (wgid >> 2) * 128, n0 = (wgid & 3) * 128;   // m-major: A-panel reuse
  const int tid = threadIdx.x;
  const int lane = tid & 63, w = tid >> 6;
  const int wr = w >> 1, wc = w & 1;
  const int l15 = lane & 15, l4 = lane >> 4;
  const int srow = lane >> 2;
  const int skk  = (lane & 3) * 8;

  f32x4 acc[4][4];
#pragma unroll
  for (int i = 0; i < 4; i++)
#pragma unroll
    for (int j = 0; j < 4; j++) acc[i][j] = (f32x4){0.f, 0.f, 0.f, 0.f};

  for (int kt = 0; kt < 8; ++kt){
    int k0 = kt * 32;
#pragma unroll
    for (int i = 0; i < 2; i++){
      int rbase = w * 32 + i * 16;
      int row = rbase + srow;
      gload16(A + (size_t)(m0 + row) * CH + k0 + skk, &As[rbase * 32]);
      gload16(B + (size_t)(n0 + row) * CH + k0 + skk, &Bs[rbase * 32]);
    }
    __syncthreads();
    bf16x8 af[4], bfr[4];
#pragma unroll
    for (int f = 0; f < 4; f++){
      af[f]  = *(const bf16x8*)&As[(wr * 64 + f * 16 + l15) * 32 + l4 * 8];
      bfr[f] = *(const bf16x8*)&Bs[(wc * 64 + f * 16 + l15) * 32 + l4 * 8];
    }
#pragma unroll
    for (int fi = 0; fi < 4; fi++)
#pragma unroll
      for (int fj = 0; fj < 4; fj++)
        acc[fi][fj] = __builtin_amdgcn_mfma_f32_16x16x32_bf16(af[fi], bfr[fj],
                                                              acc[fi][fj], 0, 0, 0);
    __syncthreads();
  }

  // epilogue: D col = lane&15, row = (lane>>4)*4 + reg [m89]; split outputs at col 256
#pragma unroll
  for (int fj = 0; fj < 4; fj++){
    int col = n0 + wc * 64 + fj * 16 + l15;
#pragma unroll
    for (int fi = 0; fi < 4; fi++){
      int rbase = m0 + wr * 64 + fi * 16 + l4 * 4;
#pragma unroll
      for (int r = 0; r < 4; r++){
        int row = rbase + r;
        if (row < M){
          if (col < CH) xlb[(size_t)row * CH + col] = __float2bfloat16(acc[fi][fj][r]);
          else          xr[(size_t)row * CH + (col - CH)] = acc[fi][fj][r];
        }
      }
    }
  }
}

// ---------------- fused LSTM step: gates GEMM + cell + JK partial ----------------
// 1-D grid 2512 with XCD swizzle, m-major (16 y-blocks of a panel share an XCD L2).
// A1:[M][256] bf16 (xs_t), A2:[M][512] bf16 (h_in, K2=0 at t=0)
// B1/B2: PERMUTED weights [2048][K] bf16; biasp: permuted bih+bhh [2048] f32
// h_out MUST differ from h_in (A2 rows are read by all y-blocks of the panel).
__global__ __launch_bounds__(256) void k_lstm_step(
    const __hip_bfloat16* __restrict__ A1, int K1,
    const __hip_bfloat16* __restrict__ A2, int K2,
    const __hip_bfloat16* __restrict__ B1, const __hip_bfloat16* __restrict__ B2,
    const float* __restrict__ biasp, __hip_bfloat16* __restrict__ h_out,
    float* __restrict__ c, const float* __restrict__ jkw,
    float* __restrict__ score, int M, int first)
{
  __shared__ __align__(16) unsigned short As[128 * 32];
  __shared__ __align__(16) unsigned short Bs[128 * 32];
  const int wgid = xcd_swz(blockIdx.x, 2512 >> 3, 2512 & 7);
  const int m0 = (wgid >> 4) * 128;
  const int yb = wgid & 15;
  const int n0 = yb * 128;
  const int tid = threadIdx.x;
  const int lane = tid & 63, w = tid >> 6;
  const int wr = w >> 1, wc = w & 1;
  const int l15 = lane & 15, l4 = lane >> 4;
  const int srow = lane >> 2;
  const int skk  = (lane & 3) * 8;

  f32x4 acc[4][4];
#pragma unroll
  for (int i = 0; i < 4; i++)
#pragma unroll
    for (int j = 0; j < 4; j++) acc[i][j] = (f32x4){0.f, 0.f, 0.f, 0.f};

  const int nt1 = K1 / 32, nt2 = K2 / 32;

  for (int kt = 0; kt < nt1 + nt2; ++kt){
    const __hip_bfloat16* Ab; const __hip_bfloat16* Bb; int K, k0;
    if (kt < nt1){ Ab = A1; Bb = B1; K = K1; k0 = kt * 32; }
    else         { Ab = A2; Bb = B2; K = K2; k0 = (kt - nt1) * 32; }
#pragma unroll
    for (int i = 0; i < 2; i++){
      int rbase = w * 32 + i * 16;
      int row = rbase + srow;
      gload16(Ab + (size_t)(m0 + row) * K + k0 + skk, &As[rbase * 32]);
      gload16(Bb + (size_t)(n0 + row) * K + k0 + skk, &Bs[rbase * 32]);
    }
    __syncthreads();
    bf16x8 af[4], bfr[4];
#pragma unroll
    for (int f = 0; f < 4; f++){
      af[f]  = *(const bf16x8*)&As[(wr * 64 + f * 16 + l15) * 32 + l4 * 8];
      bfr[f] = *(const bf16x8*)&Bs[(wc * 64 + f * 16 + l15) * 32 + l4 * 8];
    }
#pragma unroll
    for (int fi = 0; fi < 4; fi++)
#pragma unroll
      for (int fj = 0; fj < 4; fj++)
        acc[fi][fj] = __builtin_amdgcn_mfma_f32_16x16x32_bf16(af[fi], bfr[fj],
                                                              acc[fi][fj], 0, 0, 0);
    __syncthreads();
  }

  // ---- fused cell epilogue ----
  const int block64 = yb * 2 + wc;             // 0..31
  const int j = block64 * 16 + l15;            // hidden channel 0..511
  const float bi0 = biasp[block64 * 64 + l15];
  const float bi1 = biasp[block64 * 64 + 16 + l15];
  const float bi2 = biasp[block64 * 64 + 32 + l15];
  const float bi3 = biasp[block64 * 64 + 48 + l15];
  const float jw  = jkw[j];
#pragma unroll
  for (int fi = 0; fi < 4; fi++){
#pragma unroll
    for (int r = 0; r < 4; r++){
      int node = m0 + wr * 64 + fi * 16 + l4 * 4 + r;
      float p = 0.f;
      if (node < M){
        float gi = acc[fi][0][r] + bi0;
        float gf = acc[fi][1][r] + bi1;
        float gg = acc[fi][2][r] + bi2;
        float go = acc[fi][3][r] + bi3;
        size_t hb = (size_t)node * HID + j;
        float cv = first ? 0.f : c[hb];
        float iv = 1.f / (1.f + __expf(-gi));
        float fv = 1.f / (1.f + __expf(-gf));
        float ov = 1.f / (1.f + __expf(-go));
        float cn = fv * cv + iv * tanhf(gg);
        float hn = ov * tanhf(cn);
        c[hb] = cn;
        h_out[hb] = __float2bfloat16(hn);
        p = hn * jw;
      }
      p += __shfl_xor(p, 1, 64); p += __shfl_xor(p, 2, 64);
      p += __shfl_xor(p, 4, 64); p += __shfl_xor(p, 8, 64);
      if (l15 == 0 && node < M) atomicAdd(&score[node], p);
    }
  }
}

// ---------------- fused GAT message pass (bf16 gathers, 128 thr = ch pairs) ----------------
__global__ __launch_bounds__(128) void k_gat(
    const int* __restrict__ indptr, const int* __restrict__ esrc,
    const float* __restrict__ eea, const __hip_bfloat16* __restrict__ xlb,
    const float* __restrict__ xr, const float* __restrict__ We,
    const float* __restrict__ att, const float* __restrict__ bias,
    __hip_bfloat16* __restrict__ xsb)
{
  const int n = blockIdx.x;
  const int t = threadIdx.x;              // ch pair (2t, 2t+1); head = t>>5
  const int c0 = 2 * t;
  const int s0 = indptr[n], s1 = indptr[n + 1];
  const float2 xr_t = *(const float2*)&xr[(size_t)n * CH + c0];
  const float2 We_t = *(const float2*)&We[c0];
  const float2 at_t = *(const float2*)&att[c0];
  float m = -1e30f, l = 0.f;
  float2 acc = make_float2(0.f, 0.f);

  int i = s0;
  for (; i + 1 < s1; i += 2){             // 2-way unroll: both gathers in flight
    int   sA = esrc[i],  sB = esrc[i + 1];
    float aA = eea[i],   aB = eea[i + 1];
    float2 xvA = ldbf2(xlb + (size_t)sA * CH + c0);
    float2 xvB = ldbf2(xlb + (size_t)sB * CH + c0);
    float vx = xvA.x + xr_t.x + aA * We_t.x;
    float vy = xvA.y + xr_t.y + aA * We_t.y;
    vx = vx > 0.f ? vx : SLOPE * vx;
    vy = vy > 0.f ? vy : SLOPE * vy;
    float pl = vx * at_t.x + vy * at_t.y;
    pl += __shfl_xor(pl, 16, 64); pl += __shfl_xor(pl, 8, 64);
    pl += __shfl_xor(pl, 4, 64);  pl += __shfl_xor(pl, 2, 64);
    pl += __shfl_xor(pl, 1, 64);                       // lgA (per 32-lane head)
    float wx = xvB.x + xr_t.x + aB * We_t.x;
    float wy = xvB.y + xr_t.y + aB * We_t.y;
    wx = wx > 0.f ? wx : SLOPE * wx;
    wy = wy > 0.f ? wy : SLOPE * wy;
    float pm = wx * at_t.x + wy * at_t.y;
    pm += __shfl_xor(pm, 16, 64); pm += __shfl_xor(pm, 8, 64);
    pm += __shfl_xor(pm, 4, 64);  pm += __shfl_xor(pm, 2, 64);
    pm += __shfl_xor(pm, 1, 64);                       // lgB
    float mn = fmaxf(m, pl);
    float sc = __expf(m - mn), wA = __expf(pl - mn);
    l = l * sc + wA;
    acc.x = acc.x * sc + wA * xvA.x;
    acc.y = acc.y * sc + wA * xvA.y;
    m = mn;
    mn = fmaxf(m, pm);
    sc = __expf(m - mn); float wB = __expf(pm - mn);
    l = l * sc + wB;
    acc.x = acc.x * sc + wB * xvB.x;
    acc.y = acc.y * sc + wB * xvB.y;
    m = mn;
  }
  if (i < s1){
    int   sA = esrc[i];
    float aA = eea[i];
    float2 xvA = ldbf2(xlb + (size_t)sA * CH + c0);
    float vx = xvA.x + xr_t.x + aA * We_t.x;
    float vy = xvA.y + xr_t.y + aA * We_t.y;
    vx = vx > 0.f ? vx : SLOPE * vx;
    vy = vy > 0.f ? vy : SLOPE * vy;
    float pl = vx * at_t.x + vy * at_t.y;
    pl += __shfl_xor(pl, 16, 64); pl += __shfl_xor(pl, 8, 64);
    pl += __shfl_xor(pl, 4, 64);  pl += __shfl_xor(pl, 2, 64);
    pl += __shfl_xor(pl, 1, 64);
    float mn = fmaxf(m, pl);
    float sc = __expf(m - mn), wA = __expf(pl - mn);
    l = l * sc + wA;
    acc.x = acc.x * sc + wA * xvA.x;
    acc.y = acc.y * sc + wA * xvA.y;
    m = mn;
  }
  float invl = (l > 0.f) ? 1.f / l : 0.f;
  float2 bia = *(const float2*)&bias[c0];
  float ox = acc.x * invl + bia.x;
  float oy = acc.y * invl + bia.y;
  ox = ox > 0.f ? ox : 0.f;
  oy = oy > 0.f ? oy : 0.f;
  ushort2 hp;
  hp.x = __bfloat16_as_ushort(__float2bfloat16(ox));
  hp.y = __bfloat16_as_ushort(__float2bfloat16(oy));
  *(ushort2*)&xsb[(size_t)n * CH + c0] = hp;
}

// ---------------- JK softmax combine + BN reduction (fused) ----------------
__global__ __launch_bounds__(256) void k_jk(const float* __restrict__ scores,
                                            const __hip_bfloat16* __restrict__ xsb,
                                            float* __restrict__ out,
                                            float* __restrict__ sums)
{
  const int cx = threadIdx.x;
  const size_t NC = (size_t)N_NODES * CH;
  float s = 0.f, s2 = 0.f;
  for (int n = blockIdx.x; n < N_NODES; n += gridDim.x){
    float s0 = scores[n], s1 = scores[N_NODES + n];
    float sc2 = scores[2 * N_NODES + n], s3 = scores[3 * N_NODES + n];
    float mx = fmaxf(fmaxf(s0, s1), fmaxf(sc2, s3));
    float e0 = __expf(s0 - mx), e1 = __expf(s1 - mx);
    float e2 = __expf(sc2 - mx), e3 = __expf(s3 - mx);
    float inv = 1.f / (e0 + e1 + e2 + e3);
    size_t idx = (size_t)n * CH + cx;
    float v = e0 * __bfloat162float(xsb[idx]) + e1 * __bfloat162float(xsb[NC + idx]) +
              e2 * __bfloat162float(xsb[2 * NC + idx]) +
              e3 * __bfloat162float(xsb[3 * NC + idx]);
    v *= inv;
    out[idx] = v;
    s += v;
    s2 = fmaf(v, v, s2);
  }
  atomicAdd(&sums[cx], s);
  atomicAdd(&sums[CH + cx], s2);
}

__global__ __launch_bounds__(256) void k_bnapply(float* __restrict__ out,
                                                 const float* __restrict__ sums,
                                                 const float* __restrict__ gamma,
                                                 const float* __restrict__ beta)
{
  int idx = blockIdx.x * 256 + threadIdx.x;
  int cx = idx & 255;
  const float invN = 1.f / (float)N_NODES;
  float mean = sums[cx] * invN;
  float var = sums[CH + cx] * invN - mean * mean;
  out[idx] = (out[idx] - mean) * rsqrtf(var + EPS) * gamma[cx] + beta[cx];
}

// ---------------- host ----------------
extern "C" void kernel_launch(void* const* d_in, const int* in_sizes, int n_in,
                              void* d_out, int out_size, void* d_ws, size_t ws_size,
                              hipStream_t stream)
{
  const float* x     = (const float*)d_in[0];
  const int*   eidx  = (const int*)d_in[1];
  const int*   srcp  = eidx;
  const int*   dstp  = eidx + N_EDGES;
  const float* ea    = (const float*)d_in[2];
  const float* Wl0   = (const float*)d_in[3];
  const float* Wr0   = (const float*)d_in[4];
  const float* We0   = (const float*)d_in[5];
  const float* att0  = (const float*)d_in[6];
  const float* b0    = (const float*)d_in[7];
  const float* WlR   = (const float*)d_in[8];
  const float* WrR   = (const float*)d_in[9];
  const float* WeR   = (const float*)d_in[10];
  const float* attR  = (const float*)d_in[11];
  const float* bR    = (const float*)d_in[12];
  const float* Wih_f = (const float*)d_in[13];
  const float* Whh_f = (const float*)d_in[14];
  const float* bih_f = (const float*)d_in[15];
  const float* bhh_f = (const float*)d_in[16];
  const float* Wih_b = (const float*)d_in[17];
  const float* Whh_b = (const float*)d_in[18];
  const float* bih_b = (const float*)d_in[19];
  const float* bhh_b = (const float*)d_in[20];
  const float* jkw   = (const float*)d_in[21];
  const float* gamma = (const float*)d_in[23];
  const float* beta  = (const float*)d_in[24];

  // ---------- byte-precise workspace layout ----------
  char* base = (char*)d_ws;
  const size_t NC   = (size_t)N_NODES * CH;          // 5,120,000 elems
  const size_t NH   = (size_t)N_NODES * HID;         // 10,240,000 elems
  size_t off = 0;
  __hip_bfloat16* wihf_p = (__hip_bfloat16*)(base + off); off += (size_t)G4 * CH * 2;
  __hip_bfloat16* whhf_p = (__hip_bfloat16*)(base + off); off += (size_t)G4 * HID * 2;
  __hip_bfloat16* wihb_p = (__hip_bfloat16*)(base + off); off += (size_t)G4 * CH * 2;
  __hip_bfloat16* whhb_p = (__hip_bfloat16*)(base + off); off += (size_t)G4 * HID * 2;
  float* biasf_p = (float*)(base + off); off += G4 * 4;
  float* biasb_p = (float*)(base + off); off += G4 * 4;
  float* scores  = (float*)(base + off); off += (size_t)LAYERS * N_NODES * 4;
  float* sums    = (float*)(base + off); off += 2048;
  __hip_bfloat16* xsb = (__hip_bfloat16*)(base + off); off += LAYERS * NC * 2;
  const size_t R = off;                              // shared region base (~47.6 MB)
  // GAT view of R (all dead before LSTM phase)
  float* xr = (float*)(base + R);                    // [N][CH] f32 target transform
  __hip_bfloat16* xlb = (__hip_bfloat16*)(xr + NC);  // [N][CH] bf16 source transform
  int*   indptr = (int*)(xlb + NC);                  // N+1
  int*   cursor = indptr + (N_NODES + 1);            // N
  int*   esrc   = cursor + N_NODES;                  // E (dst-sorted src)
  float* eea    = (float*)(esrc + N_EDGES);          // E (dst-sorted edge_attr)
  __hip_bfloat16* wgat_p = (__hip_bfloat16*)(eea + N_EDGES);  // [3][512][256] bf16
  const size_t gat_end = R + NC * 4 + NC * 2
                       + (2 * (size_t)N_NODES + 1 + 2 * (size_t)N_EDGES) * 4
                       + 3 * (size_t)2 * CH * CH * 2;
  // LSTM view of R: h0, h1, c ordered so tail OOB reads stay interior
  __hip_bfloat16* hbuf0 = (__hip_bfloat16*)(base + R);            // [N][HID] bf16
  __hip_bfloat16* hbuf1 = (__hip_bfloat16*)(base + R + NH * 2);   // [N][HID] bf16
  float* cbuf  = (float*)(base + R + NH * 4);                     // [N][HID] f32
  const size_t lstm_end = R + NH * 4 + NH * 4;

  if (gat_end > ws_size || lstm_end > ws_size) return;  // leave output poisoned

  // ---- CSR by dst (src/ea stored dst-sorted) ----
  hipMemsetAsync(cursor, 0, N_NODES * sizeof(int), stream);
  k_hist<<<(N_EDGES + 255) / 256, 256, 0, stream>>>(dstp, cursor);
  k_scan<<<1, 1024, 0, stream>>>(cursor, indptr, cursor);
  k_scatter<<<(N_EDGES + 255) / 256, 256, 0, stream>>>(srcp, dstp, ea, cursor,
                                                       esrc, eea);

  // ---- weight prep ----
  k_wperm<<<(G4 * CH + 255) / 256, 256, 0, stream>>>(Wih_f, wihf_p, CH);
  k_wperm<<<(G4 * HID + 255) / 256, 256, 0, stream>>>(Whh_f, whhf_p, HID);
  k_wperm<<<(G4 * CH + 255) / 256, 256, 0, stream>>>(Wih_b, wihb_p, CH);
  k_wperm<<<(G4 * HID + 255) / 256, 256, 0, stream>>>(Whh_b, whhb_p, HID);
  k_bperm<<<(G4 + 255) / 256, 256, 0, stream>>>(bih_f, bhh_f, biasf_p);
  k_bperm<<<(G4 + 255) / 256, 256, 0, stream>>>(bih_b, bhh_b, biasb_p);
  for (int l = 0; l < LAYERS - 1; ++l)
    k_wtrans<<<(CH * CH + 255) / 256, 256, 0, stream>>>(
        WlR + (size_t)l * CH * CH, WrR + (size_t)l * CH * CH,
        wgat_p + (size_t)l * 2 * CH * CH);

  // ---- GATv2 layers (MFMA transforms from bf16 xs; fused message pass) ----
  for (int l = 0; l < LAYERS; ++l){
    if (l == 0){
      k_xf0<<<(int)(NC / 256), 256, 0, stream>>>(x, Wl0, Wr0, xlb, xr);
    } else {
      k_xform<<<628, 256, 0, stream>>>(
          xsb + (size_t)(l - 1) * NC, wgat_p + (size_t)(l - 1) * 2 * CH * CH,
          xlb, xr, N_NODES);
    }
    const float* We  = (l == 0) ? We0  : WeR  + (size_t)(l - 1) * CH;
    const float* att = (l == 0) ? att0 : attR + (size_t)(l - 1) * CH;
    const float* bia = (l == 0) ? b0   : bR   + (size_t)(l - 1) * CH;
    k_gat<<<N_NODES, 128, 0, stream>>>(indptr, esrc, eea, xlb, xr, We, att, bia,
                                       xsb + (size_t)l * NC);
  }

  // ---- LSTM (scores accumulated atomically; zero once) ----
  __hip_bfloat16* hb[2] = {hbuf0, hbuf1};
  hipMemsetAsync(scores, 0, (size_t)LAYERS * N_NODES * 4, stream);
  for (int t = 0; t < LAYERS; t++){
    k_lstm_step<<<2512, 256, 0, stream>>>(
        xsb + (size_t)t * NC, CH, hb[(t + 1) & 1], (t == 0) ? 0 : HID,
        wihf_p, whhf_p, biasf_p, hb[t & 1], cbuf, jkw,
        scores + (size_t)t * N_NODES, N_NODES, t == 0);
  }
  for (int s = 0; s < LAYERS; s++){
    int t = LAYERS - 1 - s;
    k_lstm_step<<<2512, 256, 0, stream>>>(
        xsb + (size_t)t * NC, CH, hb[(s + 1) & 1], (s == 0) ? 0 : HID,
        wihb_p, whhb_p, biasb_p, hb[s & 1], cbuf, jkw + HID,
        scores + (size_t)t * N_NODES, N_NODES, s == 0);
  }

  // ---- JK combine (+BN reduce) + BN apply ----
  hipMemsetAsync(sums, 0, 2048, stream);
  k_jk<<<256, 256, 0, stream>>>(scores, xsb, (float*)d_out, sums);
  k_bnapply<<<(int)(NC / 256), 256, 0, stream>>>((float*)d_out, sums, gamma, beta);
}